// Round 4
// baseline (599.033 us; speedup 1.0000x reference)
//
#include <hip/hip_runtime.h>
#include <hip/hip_bf16.h>
#include <math.h>
#include <stdint.h>

// Problem constants
#define Bc   2
#define Nc   512
#define Hc   12
#define DHc  64
#define DIMc 768
#define DPAIRc 128
#define DCONDc 512
#define INNERc 3072
#define NQc  32
#define NKc  128
#define NWc  (Nc / NQc)   // 16

typedef __attribute__((ext_vector_type(8))) short short8;
typedef __attribute__((ext_vector_type(4))) float floatx4;

// ---------------- helpers ----------------
__device__ inline float wave_sum(float v) {
#pragma unroll
  for (int off = 32; off > 0; off >>= 1) v += __shfl_xor(v, off, 64);
  return v;
}
__device__ inline float wave_max(float v) {
#pragma unroll
  for (int off = 32; off > 0; off >>= 1) v = fmaxf(v, __shfl_xor(v, off, 64));
  return v;
}
__device__ inline float block_sum(float v, float* red) {
  v = wave_sum(v);
  int wv = threadIdx.x >> 6, lane = threadIdx.x & 63;
  __syncthreads();
  if (lane == 0) red[wv] = v;
  __syncthreads();
  return red[0] + red[1] + red[2] + red[3];
}
__device__ inline float sigmoidf(float x) { return 1.0f / (1.0f + expf(-x)); }

// async global->LDS 16B DMA. LDS dest is wave-uniform base + lane*16 (m104).
__device__ __forceinline__ void gload16(const void* g, void* l) {
  __builtin_amdgcn_global_load_lds(
      reinterpret_cast<__attribute__((address_space(1))) const void*>(
          reinterpret_cast<uintptr_t>(g)),
      reinterpret_cast<__attribute__((address_space(3))) void*>(
          static_cast<uint32_t>(reinterpret_cast<uintptr_t>(l))),
      16, 0, 0);
}

// ---------------- LN over rows of cond -> bf16 ----------------
__global__ __launch_bounds__(256) void ln_rows_bf16_k(const float* __restrict__ in,
                                                      __hip_bfloat16* __restrict__ out, int C) {
  __shared__ float red[4];
  int row = blockIdx.x;
  const float* x = in + (size_t)row * C;
  float s = 0.f;
  for (int c = threadIdx.x; c < C; c += 256) s += x[c];
  float mean = block_sum(s, red) / C;
  float vs = 0.f;
  for (int c = threadIdx.x; c < C; c += 256) { float d = x[c] - mean; vs += d * d; }
  float var = block_sum(vs, red) / C;
  float r = rsqrtf(var + 1e-5f);
  for (int c = threadIdx.x; c < C; c += 256)
    out[(size_t)row * C + c] = __float2bfloat16((x[c] - mean) * r);
}

// ---------------- batched transpose+cast f32[K,N] -> bf16[N,K] ----------------
// interleave=1 (for tr_win): permute destination rows so each 32-row group is
// (16 a-cols j..j+15, 16 g-cols j..j+15) -> enables SiLU fusion in GEMM epilogue.
struct TP6 { const float* s0; const float* s1; const float* s2;
             const float* s3; const float* s4; const float* s5; };
__global__ __launch_bounds__(256) void transpose_cast_batch_k(TP6 p,
    __hip_bfloat16* __restrict__ dstBase, int K, int N, int interleave) {
  __shared__ float tile[32][33];
  const float* srcs[6] = {p.s0, p.s1, p.s2, p.s3, p.s4, p.s5};
  const float* src = srcs[blockIdx.z];
  __hip_bfloat16* dst = dstBase + (size_t)blockIdx.z * K * N;
  int k0 = blockIdx.y * 32, n0 = blockIdx.x * 32;
  int t = threadIdx.x;
  int r = t >> 5, c = t & 31;
#pragma unroll
  for (int i = 0; i < 4; ++i) tile[r + i * 8][c] = src[(size_t)(k0 + r + i * 8) * N + n0 + c];
  __syncthreads();
#pragma unroll
  for (int i = 0; i < 4; ++i) {
    int n = n0 + r + i * 8;        // source column index = dest row (pre-perm)
    int dr = n;
    if (interleave) {
      int half = N >> 1;
      dr = (n < half) ? (((n >> 4) << 5) + (n & 15))
                      : ((((n - half) >> 4) << 5) + 16 + ((n - half) & 15));
    }
    dst[(size_t)dr * K + k0 + c] = __float2bfloat16(tile[c][r + i * 8]);
  }
}

// ---------------- concat biases + wbT pack + colsum ----------------
__global__ __launch_bounds__(256) void concat_bias_k(
    const float* __restrict__ a1_gb, const float* __restrict__ s1_b,
    const float* __restrict__ a2_gb, const float* __restrict__ s2_b,
    const float* __restrict__ bq, const float* __restrict__ bk,
    const float* __restrict__ bv, const float* __restrict__ bg,
    const float* __restrict__ wb_pair,
    float* __restrict__ cb6, float* __restrict__ bqkvg,
    __hip_bfloat16* __restrict__ wbT, float* __restrict__ colsum) {
  int i = blockIdx.x * 256 + threadIdx.x;
  if (i < 6 * DIMc) {
    int seg = i / DIMc, o = i - seg * DIMc;
    float v = 0.f;
    if (seg == 0) v = a1_gb[o];
    else if (seg == 2) v = s1_b[o];
    else if (seg == 3) v = a2_gb[o];
    else if (seg == 5) v = s2_b[o];
    cb6[i] = v;
  }
  if (i < 4 * DIMc) {
    int seg = i / DIMc, o = i - seg * DIMc;
    bqkvg[i] = (seg == 0) ? bq[o] : (seg == 1) ? bk[o] : (seg == 2) ? bv[o] : bg[o];
  }
  if (i < 16 * DPAIRc) {
    int h = i >> 7, c = i & 127;
    wbT[i] = (h < Hc) ? __float2bfloat16(wb_pair[c * Hc + h]) : __float2bfloat16(0.f);
  }
  if (blockIdx.x == 0 && threadIdx.x < 16) {
    int h = threadIdx.x;
    float s = 0.f;
    if (h < Hc)
      for (int c = 0; c < DPAIRc; ++c)
        s += __bfloat162float(__float2bfloat16(wb_pair[c * Hc + h]));
    colsum[h] = s;
  }
}

// ---------------- bf16 MFMA GEMM: C[M,N] = A[M,K] @ Bt[N,K]^T + epilogue -------
// global_load_lds width=16 staging + T3/T4: 2-deep pipeline with COUNTED vmcnt
// (never drain to 0 in the main loop) + raw s_barrier (no auto vmcnt(0) drain).
// mode 3: SiLU-pair epilogue (Bt rows interleaved a/g by 16) -> bf16 C, N/2 cols.
template <int WNT>
__global__ __launch_bounds__(256) void gemm_bf16_k(
    const __hip_bfloat16* __restrict__ A, const __hip_bfloat16* __restrict__ Bt,
    float* __restrict__ C, int M, int N, int K,
    const float* __restrict__ bias,
    const float* __restrict__ ss, int ssst,
    const float* __restrict__ resid, const float* __restrict__ maskp, int mode) {
  constexpr int TN = 32 * WNT;
  __shared__ __align__(16) __hip_bfloat16 As[2][128 * 32];
  __shared__ __align__(16) __hip_bfloat16 Bs[2][TN * 32];
  int tid = threadIdx.x;
  int lane = tid & 63, wv = tid >> 6;
  int l16 = lane & 15, quad = lane >> 4;
  int m0 = blockIdx.y * 128, n0 = blockIdx.x * TN;
  int wm0 = (wv >> 1) * 64, wn0 = (wv & 1) * (16 * WNT);

  // staging geometry: thread t covers 16B slot t (and t+256 for 128-row tiles)
  int srow = tid >> 2;            // 0..63
  int skc = (tid & 3) * 8;        // bf16 column within 32-wide K-tile
  const __hip_bfloat16* Ab  = A  + (size_t)(m0 + srow) * K + skc;
  const __hip_bfloat16* Ab2 = Ab + (size_t)64 * K;
  const __hip_bfloat16* Bb  = Bt + (size_t)(n0 + srow) * K + skc;
  const __hip_bfloat16* Bb2 = Bb + (size_t)64 * K;
  __hip_bfloat16* AsW0 = &As[0][0] + wv * 512;   // wave-uniform LDS bases
  __hip_bfloat16* AsW1 = &As[1][0] + wv * 512;
  __hip_bfloat16* BsW0 = &Bs[0][0] + wv * 512;
  __hip_bfloat16* BsW1 = &Bs[1][0] + wv * 512;

  floatx4 acc[4][WNT];
#pragma unroll
  for (int mi = 0; mi < 4; ++mi)
#pragma unroll
    for (int nj = 0; nj < WNT; ++nj) acc[mi][nj] = (floatx4){0.f, 0.f, 0.f, 0.f};

  auto stage = [&](int kk, __hip_bfloat16* AW, __hip_bfloat16* BW) {
    gload16(Ab + kk, AW);
    gload16(Ab2 + kk, AW + 2048);
    if (WNT == 4) {
      gload16(Bb + kk, BW);
      gload16(Bb2 + kk, BW + 2048);
    } else {
      if (wv < 2) gload16(Bb + kk, BW);
    }
  };
  auto compute = [&](const __hip_bfloat16* Asb, const __hip_bfloat16* Bsb) {
    short8 a[4], b[WNT];
#pragma unroll
    for (int mi = 0; mi < 4; ++mi)
      a[mi] = *(const short8*)(const void*)&Asb[(wm0 + mi * 16 + l16) * 32 + quad * 8];
#pragma unroll
    for (int nj = 0; nj < WNT; ++nj)
      b[nj] = *(const short8*)(const void*)&Bsb[(wn0 + nj * 16 + l16) * 32 + quad * 8];
#pragma unroll
    for (int mi = 0; mi < 4; ++mi)
#pragma unroll
      for (int nj = 0; nj < WNT; ++nj)
        acc[mi][nj] = __builtin_amdgcn_mfma_f32_16x16x32_bf16(a[mi], b[nj], acc[mi][nj], 0, 0, 0);
  };

  // T3/T4 pipeline: 2 K-tiles in flight; counted vmcnt; raw barriers.
  int nt = K >> 5;                 // number of 32-wide K-tiles (>= 16 here)
  stage(0, AsW0, BsW0);            // tile 0 -> buf0
  stage(32, AsW1, BsW1);           // tile 1 -> buf1
  for (int t = 0; t < nt; ++t) {
    // wait until tile t's loads (oldest L in the queue) have landed,
    // leaving tile t+1's loads in flight (vmcnt(L)), except on the last tile.
    if (t < nt - 1) {
      if (WNT == 4) {
        asm volatile("s_waitcnt vmcnt(4)" ::: "memory");
      } else {
        if (wv < 2) asm volatile("s_waitcnt vmcnt(3)" ::: "memory");
        else        asm volatile("s_waitcnt vmcnt(2)" ::: "memory");
      }
    } else {
      asm volatile("s_waitcnt vmcnt(0)" ::: "memory");
    }
    __builtin_amdgcn_s_barrier();          // buffer t%2 fully staged for all waves
    __builtin_amdgcn_sched_barrier(0);
    if (t & 1) compute(&As[1][0], &Bs[1][0]);
    else       compute(&As[0][0], &Bs[0][0]);
    __builtin_amdgcn_sched_barrier(0);
    __builtin_amdgcn_s_barrier();          // all waves done reading buffer t%2
    if (t + 2 < nt) {
      int kk = (t + 2) << 5;
      if (t & 1) stage(kk, AsW1, BsW1);
      else       stage(kk, AsW0, BsW0);
    }
  }

  if (mode == 3) {
    if constexpr (WNT >= 2) {
      __hip_bfloat16* Cb = (__hip_bfloat16*)C;
      int halfN = N >> 1;
#pragma unroll
      for (int mi = 0; mi < 4; ++mi) {
#pragma unroll
        for (int njp = 0; njp < WNT / 2; ++njp) {
          int outcol = ((n0 + wn0) >> 1) + njp * 16 + l16;
#pragma unroll
          for (int r = 0; r < 4; ++r) {
            int m = m0 + wm0 + mi * 16 + quad * 4 + r;
            float av = acc[mi][2 * njp][r];
            float gv = acc[mi][2 * njp + 1][r];
            Cb[(size_t)m * halfN + outcol] = __float2bfloat16(av * gv * sigmoidf(gv));
          }
        }
      }
    }
    return;
  }

#pragma unroll
  for (int mi = 0; mi < 4; ++mi) {
#pragma unroll
    for (int nj = 0; nj < WNT; ++nj) {
      int ncol = n0 + wn0 + nj * 16 + l16;
      float bb = bias ? bias[ncol] : 0.f;
#pragma unroll
      for (int r = 0; r < 4; ++r) {
        int m = m0 + wm0 + mi * 16 + quad * 4 + r;
        float v = acc[mi][nj][r] + bb;
        if (mode == 1) {
          float mk = maskp[m];
          v *= sigmoidf(ss[(size_t)m * ssst + ncol]) * mk * mk;
          v = (v + resid[(size_t)m * N + ncol]) * mk;
        } else if (mode == 2) {
          float mk = maskp[m];
          v = v * mk * sigmoidf(ss[(size_t)m * ssst + ncol]) * mk * mk;
          v = (v + resid[(size_t)m * N + ncol]) * mk * mk;
        }
        C[(size_t)m * N + ncol] = v;
      }
    }
  }
}

// ---------------- adaLN apply (raw proj inputs, sigmoid fused) ----------------
__global__ __launch_bounds__(256) void adaln_apply_k(
    const float* __restrict__ xin, const float* __restrict__ maskp,
    const float* __restrict__ graw, const float* __restrict__ braw, int ssst,
    __hip_bfloat16* __restrict__ xa, float* __restrict__ xm) {
  __shared__ float red[4];
  int row = blockIdx.x;
  float mk = maskp[row];
  const float* xr = xin + (size_t)row * DIMc;
  float vals[3];
  float s = 0.f;
#pragma unroll
  for (int it = 0; it < 3; ++it) {
    int c = threadIdx.x + it * 256;
    float v = xr[c] * mk;
    vals[it] = v;
    s += v;
  }
  float mean = block_sum(s, red) * (1.0f / DIMc);
  float vs = 0.f;
#pragma unroll
  for (int it = 0; it < 3; ++it) { float d = vals[it] - mean; vs += d * d; }
  float var = block_sum(vs, red) * (1.0f / DIMc);
  float r = rsqrtf(var + 1e-5f);
#pragma unroll
  for (int it = 0; it < 3; ++it) {
    int c = threadIdx.x + it * 256;
    size_t sidx = (size_t)row * ssst + c;
    if (xm) xm[(size_t)row * DIMc + c] = vals[it];
    float o = ((vals[it] - mean) * r * sigmoidf(graw[sidx]) + braw[sidx]) * mk;
    xa[(size_t)row * DIMc + c] = __float2bfloat16(o);
  }
}

// ---------------- windowed pair bias via MFMA + post-LN fixup ----------------
__global__ __launch_bounds__(256) void pair_bias_mfma_k(
    const float* __restrict__ pr, const __hip_bfloat16* __restrict__ wbT,
    const float* __restrict__ colsum, float* __restrict__ biasw) {
  constexpr int LDR = 136;
  __shared__ __hip_bfloat16 rows[128 * LDR];
  __shared__ float meanS[128];
  __shared__ float rstdS[128];
  int bi = blockIdx.x;           // b*512 + i
  int i = bi & (Nc - 1), b = bi >> 9;
  int w = i >> 5, qi = i & 31;
  int j0 = w * NQc - 48;
  int t = threadIdx.x;
  int sub = t >> 5;
  int c4 = t & 31;
  const float* prb = pr + (size_t)bi * (Nc * DPAIRc);
#pragma unroll
  for (int step = 0; step < 16; ++step) {
    int row = step * 8 + sub;
    int jc = min(max(j0 + row, 0), Nc - 1);
    float4 v = *(const float4*)(prb + (size_t)jc * DPAIRc + c4 * 4);
    union { __hip_bfloat16 h[4]; uint2 u; } pk;
    pk.h[0] = __float2bfloat16(v.x); pk.h[1] = __float2bfloat16(v.y);
    pk.h[2] = __float2bfloat16(v.z); pk.h[3] = __float2bfloat16(v.w);
    *(uint2*)(void*)&rows[row * LDR + c4 * 4] = pk.u;
    float s = v.x + v.y + v.z + v.w;
    float s2 = v.x * v.x + v.y * v.y + v.z * v.z + v.w * v.w;
#pragma unroll
    for (int off = 16; off > 0; off >>= 1) {
      s += __shfl_xor(s, off, 64);
      s2 += __shfl_xor(s2, off, 64);
    }
    if (c4 == 0) {
      float mean = s * (1.0f / 128.0f);
      float var = s2 * (1.0f / 128.0f) - mean * mean;
      meanS[row] = mean;
      rstdS[row] = rsqrtf(var + 1e-5f);
    }
  }
  __syncthreads();
  int lane = t & 63, wv = t >> 6;
  int l16 = lane & 15, quad = lane >> 4;
  short8 bfrag[4];
#pragma unroll
  for (int ks = 0; ks < 4; ++ks)
    bfrag[ks] = *(const short8*)(const void*)&wbT[l16 * 128 + ks * 32 + quad * 8];
  float cs = colsum[l16];
#pragma unroll
  for (int mt = 0; mt < 2; ++mt) {
    int mtile = wv * 2 + mt;
    floatx4 acc = (floatx4){0.f, 0.f, 0.f, 0.f};
#pragma unroll
    for (int ks = 0; ks < 4; ++ks) {
      short8 a = *(const short8*)(const void*)&rows[(mtile * 16 + l16) * LDR + ks * 32 + quad * 8];
      acc = __builtin_amdgcn_mfma_f32_16x16x32_bf16(a, bfrag[ks], acc, 0, 0, 0);
    }
    if (l16 < Hc) {
      int m0r = mtile * 16 + quad * 4;
      float4 ov;
      float* po = &ov.x;
#pragma unroll
      for (int r = 0; r < 4; ++r) {
        int m = m0r + r;
        po[r] = rstdS[m] * (acc[r] - meanS[m] * cs);
      }
      *(float4*)&biasw[((((size_t)(b * Hc + l16)) * NWc + w) * NQc + qi) * NKc + m0r] = ov;
    }
  }
}

// ---------------- windowed attention v3: fused LN+RoPE staging, MFMA QK^T/PV --
__global__ __launch_bounds__(256) void wattn_k(
    const float* __restrict__ qkvg, const float* __restrict__ biasw,
    const float* __restrict__ pair_mask, __hip_bfloat16* __restrict__ o) {
  constexpr int LQ = 72;    // shorts per q/k row (64 + 8 pad)
  constexpr int LV = 136;   // shorts per vT row (128 keys + 8 pad)
  constexpr int LS = 132;   // floats per score row
  constexpr int LP = 136;   // shorts per P row
  __shared__ __hip_bfloat16 qs[32 * LQ];
  __shared__ __hip_bfloat16 ks[128 * LQ];
  __shared__ __hip_bfloat16 vT[64 * LV];
  __shared__ float sc[32 * LS];
  __shared__ __hip_bfloat16 scP[32 * LP];
  const int QS = 4 * DIMc;  // 3072
  int blk = blockIdx.x;     // (b*Hc + h)*NWc + w
  int w = blk & (NWc - 1);
  int bh = blk >> 4;
  int h = bh % Hc;
  int b = bh / Hc;
  int t = threadIdx.x;
  int j0 = w * NQc - 48;
  // stage q (bf16) with fused LN(64) + RoPE.  16 lanes per row.
  for (int e = t; e < 512; e += 256) {
    int qrow = e >> 4, c4 = e & 15;
    float4 v = *(const float4*)&qkvg[(size_t)(b * Nc + w * NQc + qrow) * QS + h * DHc + c4 * 4];
    float s = v.x + v.y + v.z + v.w;
    float s2 = v.x * v.x + v.y * v.y + v.z * v.z + v.w * v.w;
#pragma unroll
    for (int off = 1; off < 16; off <<= 1) {
      s += __shfl_xor(s, off, 64);
      s2 += __shfl_xor(s2, off, 64);
    }
    float mean = s * (1.0f / 64.0f);
    float rr = rsqrtf(s2 * (1.0f / 64.0f) - mean * mean + 1e-5f);
    float qn0 = (v.x - mean) * rr, qn1 = (v.y - mean) * rr;
    float qn2 = (v.z - mean) * rr, qn3 = (v.w - mean) * rr;
    float pos = (float)(w * NQc + qrow);
    float inv0 = exp2f(-(float)(c4 * 2) * 0.415241011861f);
    float inv1 = exp2f(-(float)(c4 * 2 + 1) * 0.415241011861f);
    float a0 = pos * inv0, a1 = pos * inv1;
    float c0 = cosf(a0), sn0 = sinf(a0), c1 = cosf(a1), sn1 = sinf(a1);
    union { __hip_bfloat16 hh[4]; uint2 u; } pk;
    pk.hh[0] = __float2bfloat16(qn0 * c0 - qn1 * sn0);
    pk.hh[1] = __float2bfloat16(qn0 * sn0 + qn1 * c0);
    pk.hh[2] = __float2bfloat16(qn2 * c1 - qn3 * sn1);
    pk.hh[3] = __float2bfloat16(qn2 * sn1 + qn3 * c1);
    *(uint2*)(void*)&qs[qrow * LQ + c4 * 4] = pk.u;
  }
  // stage k (fused LN+RoPE, row-major) and v (raw, transposed)
  for (int e = t; e < 2048; e += 256) {
    int kk = e >> 4, c4 = e & 15;
    int jc = min(max(j0 + kk, 0), Nc - 1);
    size_t src = (size_t)(b * Nc + jc) * QS + h * DHc + c4 * 4;
    float4 kv = *(const float4*)&qkvg[src + DIMc];
    float4 vv = *(const float4*)&qkvg[src + 2 * DIMc];
    float s = kv.x + kv.y + kv.z + kv.w;
    float s2 = kv.x * kv.x + kv.y * kv.y + kv.z * kv.z + kv.w * kv.w;
#pragma unroll
    for (int off = 1; off < 16; off <<= 1) {
      s += __shfl_xor(s, off, 64);
      s2 += __shfl_xor(s2, off, 64);
    }
    float mean = s * (1.0f / 64.0f);
    float rr = rsqrtf(s2 * (1.0f / 64.0f) - mean * mean + 1e-5f);
    float kn0 = (kv.x - mean) * rr, kn1 = (kv.y - mean) * rr;
    float kn2 = (kv.z - mean) * rr, kn3 = (kv.w - mean) * rr;
    float pos = (float)jc;
    float inv0 = exp2f(-(float)(c4 * 2) * 0.415241011861f);
    float inv1 = exp2f(-(float)(c4 * 2 + 1) * 0.415241011861f);
    float a0 = pos * inv0, a1 = pos * inv1;
    float c0 = cosf(a0), sn0 = sinf(a0), c1 = cosf(a1), sn1 = sinf(a1);
    union { __hip_bfloat16 hh[4]; uint2 u; } pk;
    pk.hh[0] = __float2bfloat16(kn0 * c0 - kn1 * sn0);
    pk.hh[1] = __float2bfloat16(kn0 * sn0 + kn1 * c0);
    pk.hh[2] = __float2bfloat16(kn2 * c1 - kn3 * sn1);
    pk.hh[3] = __float2bfloat16(kn2 * sn1 + kn3 * c1);
    *(uint2*)(void*)&ks[kk * LQ + c4 * 4] = pk.u;
    vT[(c4 * 4 + 0) * LV + kk] = __float2bfloat16(vv.x);
    vT[(c4 * 4 + 1) * LV + kk] = __float2bfloat16(vv.y);
    vT[(c4 * 4 + 2) * LV + kk] = __float2bfloat16(vv.z);
    vT[(c4 * 4 + 3) * LV + kk] = __float2bfloat16(vv.w);
  }
  // pre-fill score buffer with bias or -inf (mask/validity)
  for (int e = t; e < 4096; e += 256) {
    int qrow = e >> 7, key = e & 127;
    int j = j0 + key;
    bool valid = (j >= 0) && (j < Nc);
    int jc = min(max(j, 0), Nc - 1);
    float pm = pair_mask[((size_t)(b * Nc + w * NQc + qrow)) * Nc + jc];
    bool ok = valid && (pm > 0.f);
    sc[qrow * LS + key] = ok ? biasw[((size_t)blk * 32 + qrow) * 128 + key] : -1e30f;
  }
  __syncthreads();
  int lane = t & 63, wv = t >> 6;
  int l16 = lane & 15, quad = lane >> 4;
  // QK^T: wave wv handles keys [wv*32, wv*32+32), both m-tiles
  {
    short8 bfr[2][2];
#pragma unroll
    for (int nt = 0; nt < 2; ++nt)
#pragma unroll
      for (int k2 = 0; k2 < 2; ++k2)
        bfr[nt][k2] = *(const short8*)(const void*)&ks[(wv * 32 + nt * 16 + l16) * LQ + k2 * 32 + quad * 8];
#pragma unroll
    for (int mi = 0; mi < 2; ++mi) {
      short8 afr[2];
#pragma unroll
      for (int k2 = 0; k2 < 2; ++k2)
        afr[k2] = *(const short8*)(const void*)&qs[(mi * 16 + l16) * LQ + k2 * 32 + quad * 8];
#pragma unroll
      for (int nt = 0; nt < 2; ++nt) {
        floatx4 acc = (floatx4){0.f, 0.f, 0.f, 0.f};
        acc = __builtin_amdgcn_mfma_f32_16x16x32_bf16(afr[0], bfr[nt][0], acc, 0, 0, 0);
        acc = __builtin_amdgcn_mfma_f32_16x16x32_bf16(afr[1], bfr[nt][1], acc, 0, 0, 0);
        int key = wv * 32 + nt * 16 + l16;
#pragma unroll
        for (int r = 0; r < 4; ++r) {
          int m = mi * 16 + quad * 4 + r;
          float sv = sc[m * LS + key];
          if (sv > -1e29f) sc[m * LS + key] = sv + acc[r] * 0.125f;
        }
      }
    }
  }
  __syncthreads();
  // softmax: wave per 8 rows, write P as bf16
#pragma unroll
  for (int rr = 0; rr < 8; ++rr) {
    int qq = wv * 8 + rr;
    float v0 = sc[qq * LS + lane], v1 = sc[qq * LS + 64 + lane];
    float mx = wave_max(fmaxf(v0, v1));
    float e0 = expf(v0 - mx), e1 = expf(v1 - mx);
    float inv = 1.0f / wave_sum(e0 + e1);
    scP[qq * LP + lane] = __float2bfloat16(e0 * inv);
    scP[qq * LP + 64 + lane] = __float2bfloat16(e1 * inv);
  }
  __syncthreads();
  // PV: wave wv handles d-range [wv*16, wv*16+16), both m-tiles
  {
    short8 vb[4];
#pragma unroll
    for (int k4 = 0; k4 < 4; ++k4)
      vb[k4] = *(const short8*)(const void*)&vT[(wv * 16 + l16) * LV + k4 * 32 + quad * 8];
#pragma unroll
    for (int mi = 0; mi < 2; ++mi) {
      floatx4 acc = (floatx4){0.f, 0.f, 0.f, 0.f};
#pragma unroll
      for (int k4 = 0; k4 < 4; ++k4) {
        short8 pa = *(const short8*)(const void*)&scP[(mi * 16 + l16) * LP + k4 * 32 + quad * 8];
        acc = __builtin_amdgcn_mfma_f32_16x16x32_bf16(pa, vb[k4], acc, 0, 0, 0);
      }
      int d = wv * 16 + l16;
#pragma unroll
      for (int r = 0; r < 4; ++r) {
        int m = mi * 16 + quad * 4 + r;
        size_t mrow = (size_t)(b * Nc + w * NQc + m);
        float g = qkvg[mrow * QS + 3 * DIMc + h * DHc + d];
        o[mrow * DIMc + h * DHc + d] = __float2bfloat16(acc[r] * sigmoidf(g));
      }
    }
  }
}

extern "C" void kernel_launch(void* const* d_in, const int* in_sizes, int n_in,
                              void* d_out, int out_size, void* d_ws, size_t ws_size,
                              hipStream_t stream) {
  const float* x        = (const float*)d_in[0];
  const float* pair_rep = (const float*)d_in[1];
  const float* cond     = (const float*)d_in[2];
  const float* mask     = (const float*)d_in[3];
  const float* pair_mask= (const float*)d_in[4];
  const float* a1_gw    = (const float*)d_in[5];
  const float* a1_gb    = (const float*)d_in[6];
  const float* a1_bw    = (const float*)d_in[7];
  const float* wq       = (const float*)d_in[8];
  const float* bq       = (const float*)d_in[9];
  const float* wk       = (const float*)d_in[10];
  const float* bk       = (const float*)d_in[11];
  const float* wv       = (const float*)d_in[12];
  const float* bv       = (const float*)d_in[13];
  const float* wg       = (const float*)d_in[14];
  const float* bg       = (const float*)d_in[15];
  const float* wb_pair  = (const float*)d_in[16];
  const float* wo       = (const float*)d_in[17];
  const float* bo       = (const float*)d_in[18];
  const float* s1_w     = (const float*)d_in[19];
  const float* s1_b     = (const float*)d_in[20];
  const float* a2_gw    = (const float*)d_in[21];
  const float* a2_gb    = (const float*)d_in[22];
  const float* a2_bw    = (const float*)d_in[23];
  const float* tr_win   = (const float*)d_in[24];
  const float* tr_wout  = (const float*)d_in[25];
  const float* s2_w     = (const float*)d_in[26];
  const float* s2_b     = (const float*)d_in[27];
  float* out = (float*)d_out;

  const int M = Bc * Nc;  // 1024
  char* wsb = (char*)d_ws;
  size_t off = 0;
  auto alloc = [&](size_t bytes) { void* p = wsb + off; off += (bytes + 255) & ~(size_t)255; return p; };

  __hip_bfloat16* cnb     = (__hip_bfloat16*)alloc((size_t)M * DCONDc * 2);
  __hip_bfloat16* Wc6t    = (__hip_bfloat16*)alloc((size_t)6 * DIMc * DCONDc * 2);
  __hip_bfloat16* Wqkvg5t = (__hip_bfloat16*)alloc((size_t)5 * DIMc * DIMc * 2);
  __hip_bfloat16* twint   = (__hip_bfloat16*)alloc((size_t)2 * INNERc * DIMc * 2);
  __hip_bfloat16* twoutt  = (__hip_bfloat16*)alloc((size_t)DIMc * INNERc * 2);
  float* cb6    = (float*)alloc((size_t)6 * DIMc * 4);
  float* bqkvg  = (float*)alloc((size_t)4 * DIMc * 4);
  __hip_bfloat16* wbT = (__hip_bfloat16*)alloc((size_t)16 * DPAIRc * 2);
  float* colsum = (float*)alloc(16 * 4);
  float* proj_c = (float*)alloc((size_t)M * 6 * DIMc * 4);
  float* xm     = (float*)alloc((size_t)M * DIMc * 4);
  __hip_bfloat16* xa = (__hip_bfloat16*)alloc((size_t)M * DIMc * 2);
  float* qkvg   = (float*)alloc((size_t)M * 4 * DIMc * 4);
  float* biasw  = (float*)alloc((size_t)Bc * Hc * NWc * NQc * NKc * 4);
  __hip_bfloat16* obg = (__hip_bfloat16*)alloc((size_t)M * DIMc * 2);
  float* x2     = (float*)alloc((size_t)M * DIMc * 4);
  __hip_bfloat16* xt = (__hip_bfloat16*)alloc((size_t)M * DIMc * 2);
  __hip_bfloat16* actb = (__hip_bfloat16*)alloc((size_t)M * INNERc * 2);
  __hip_bfloat16* wot = Wqkvg5t + (size_t)4 * DIMc * DIMc;
  (void)ws_size; (void)in_sizes; (void)n_in; (void)out_size;

  dim3 blk(256);

  ln_rows_bf16_k<<<M, blk, 0, stream>>>(cond, cnb, DCONDc);

  transpose_cast_batch_k<<<dim3(DIMc / 32, DCONDc / 32, 6), blk, 0, stream>>>(
      TP6{a1_gw, a1_bw, s1_w, a2_gw, a2_bw, s2_w}, Wc6t, DCONDc, DIMc, 0);
  transpose_cast_batch_k<<<dim3(DIMc / 32, DIMc / 32, 5), blk, 0, stream>>>(
      TP6{wq, wk, wv, wg, wo, wo}, Wqkvg5t, DIMc, DIMc, 0);
  transpose_cast_batch_k<<<dim3(2 * INNERc / 32, DIMc / 32, 1), blk, 0, stream>>>(
      TP6{tr_win, tr_win, tr_win, tr_win, tr_win, tr_win}, twint, DIMc, 2 * INNERc, 1);
  transpose_cast_batch_k<<<dim3(DIMc / 32, INNERc / 32, 1), blk, 0, stream>>>(
      TP6{tr_wout, tr_wout, tr_wout, tr_wout, tr_wout, tr_wout}, twoutt, INNERc, DIMc, 0);

  concat_bias_k<<<(6 * DIMc + 255) / 256, blk, 0, stream>>>(
      a1_gb, s1_b, a2_gb, s2_b, bq, bk, bv, bg, wb_pair, cb6, bqkvg, wbT, colsum);

  gemm_bf16_k<4><<<dim3(6 * DIMc / 128, M / 128), blk, 0, stream>>>(
      cnb, Wc6t, proj_c, M, 6 * DIMc, DCONDc, cb6, nullptr, 0, nullptr, nullptr, 0);

  adaln_apply_k<<<M, blk, 0, stream>>>(x, mask, proj_c + 0, proj_c + DIMc, 6 * DIMc, xa, xm);

  gemm_bf16_k<4><<<dim3(4 * DIMc / 128, M / 128), blk, 0, stream>>>(
      xa, Wqkvg5t, qkvg, M, 4 * DIMc, DIMc, bqkvg, nullptr, 0, nullptr, nullptr, 0);

  pair_bias_mfma_k<<<Bc * Nc, blk, 0, stream>>>(pair_rep, wbT, colsum, biasw);

  wattn_k<<<Bc * Hc * NWc, blk, 0, stream>>>(qkvg, biasw, pair_mask, obg);

  gemm_bf16_k<1><<<dim3(DIMc / 32, M / 128), blk, 0, stream>>>(
      obg, wot, x2, M, DIMc, DIMc, bo, proj_c + 2 * DIMc, 6 * DIMc, xm, mask, 1);

  adaln_apply_k<<<M, blk, 0, stream>>>(x2, mask, proj_c + 3 * DIMc, proj_c + 4 * DIMc,
                                       6 * DIMc, xt, nullptr);

  gemm_bf16_k<4><<<dim3(2 * INNERc / 128, M / 128), blk, 0, stream>>>(
      xt, twint, (float*)actb, M, 2 * INNERc, DIMc, nullptr, nullptr, 0, nullptr, nullptr, 3);

  gemm_bf16_k<1><<<dim3(DIMc / 32, M / 128), blk, 0, stream>>>(
      actb, twoutt, out, M, DIMc, INNERc, nullptr, proj_c + 5 * DIMc, 6 * DIMc, x2, mask, 2);
}

// Round 5
// 568.232 us; speedup vs baseline: 1.0542x; 1.0542x over previous
//
#include <hip/hip_runtime.h>
#include <hip/hip_bf16.h>
#include <math.h>
#include <stdint.h>

// Problem constants
#define Bc   2
#define Nc   512
#define Hc   12
#define DHc  64
#define DIMc 768
#define DPAIRc 128
#define DCONDc 512
#define INNERc 3072
#define NQc  32
#define NKc  128
#define NWc  (Nc / NQc)   // 16

typedef __attribute__((ext_vector_type(8))) short short8;
typedef __attribute__((ext_vector_type(4))) float floatx4;

// ---------------- helpers ----------------
__device__ inline float wave_sum(float v) {
#pragma unroll
  for (int off = 32; off > 0; off >>= 1) v += __shfl_xor(v, off, 64);
  return v;
}
__device__ inline float wave_max(float v) {
#pragma unroll
  for (int off = 32; off > 0; off >>= 1) v = fmaxf(v, __shfl_xor(v, off, 64));
  return v;
}
__device__ inline float block_sum(float v, float* red) {
  v = wave_sum(v);
  int wv = threadIdx.x >> 6, lane = threadIdx.x & 63;
  __syncthreads();
  if (lane == 0) red[wv] = v;
  __syncthreads();
  return red[0] + red[1] + red[2] + red[3];
}
__device__ inline float sigmoidf(float x) { return 1.0f / (1.0f + expf(-x)); }

// async global->LDS 16B DMA. LDS dest is wave-uniform base + lane*16 (m104).
__device__ __forceinline__ void gload16(const void* g, void* l) {
  __builtin_amdgcn_global_load_lds(
      reinterpret_cast<__attribute__((address_space(1))) const void*>(
          reinterpret_cast<uintptr_t>(g)),
      reinterpret_cast<__attribute__((address_space(3))) void*>(
          static_cast<uint32_t>(reinterpret_cast<uintptr_t>(l))),
      16, 0, 0);
}

// ---------------- fused prep kernel -------------------------------------------
// One launch replaces: ln_rows, 4x transpose_cast, concat_bias, + rope table.
// Regions switched on blockIdx.x; all regions independent.
struct PrepArgs {
  const float *a1_gw, *a1_bw, *s1_w, *a2_gw, *a2_bw, *s2_w;
  const float *wq, *wk, *wv, *wg, *wo;
  const float *tr_win, *tr_wout;
  const float *cond;
  const float *a1_gb, *s1_b, *a2_gb, *s2_b;
  const float *bq, *bk, *bv, *bg, *wb_pair;
  __hip_bfloat16 *Wc6t, *Wqkvg5t, *twint, *twoutt, *cnb, *wbT;
  float *cb6, *bqkvg, *colsum, *rope;
};

#define PR_T1 2304                 // Wc6t tiles   (24 x 16 x 6)
#define PR_T2 (PR_T1 + 2880)       // Wqkvg5t      (24 x 24 x 5)
#define PR_T3 (PR_T2 + 4608)       // twint        (192 x 24), interleaved
#define PR_T4 (PR_T3 + 2304)       // twoutt       (24 x 96)
#define PR_LN (PR_T4 + 1024)       // ln_rows cond
#define PR_CB (PR_LN + 18)         // concat bias
#define PR_RT (PR_CB + 64)         // rope table (512 x 32)

__device__ __forceinline__ void do_transpose(float (*tile)[33], const float* __restrict__ src,
    __hip_bfloat16* __restrict__ dst, int K, int N, int bxx, int byy, int interleave, int t) {
  int k0 = byy * 32, n0 = bxx * 32;
  int r = t >> 5, c = t & 31;
#pragma unroll
  for (int i = 0; i < 4; ++i) tile[r + i * 8][c] = src[(size_t)(k0 + r + i * 8) * N + n0 + c];
  __syncthreads();
#pragma unroll
  for (int i = 0; i < 4; ++i) {
    int n = n0 + r + i * 8;
    int dr = n;
    if (interleave) {
      int half = N >> 1;
      dr = (n < half) ? (((n >> 4) << 5) + (n & 15))
                      : ((((n - half) >> 4) << 5) + 16 + ((n - half) & 15));
    }
    dst[(size_t)dr * K + k0 + c] = __float2bfloat16(tile[c][r + i * 8]);
  }
}

__global__ __launch_bounds__(256) void prep_k(PrepArgs p) {
  __shared__ float tile[32][33];
  __shared__ float red[4];
  int bx = blockIdx.x, t = threadIdx.x;
  if (bx < PR_T1) {
    int z = bx / 384, rem = bx - z * 384;
    int by = rem / 24, bxx = rem - by * 24;
    const float* srcs[6] = {p.a1_gw, p.a1_bw, p.s1_w, p.a2_gw, p.a2_bw, p.s2_w};
    do_transpose(tile, srcs[z], p.Wc6t + (size_t)z * DIMc * DCONDc, DCONDc, DIMc, bxx, by, 0, t);
  } else if (bx < PR_T2) {
    int l = bx - PR_T1;
    int z = l / 576, rem = l - z * 576;
    int by = rem / 24, bxx = rem - by * 24;
    const float* srcs[5] = {p.wq, p.wk, p.wv, p.wg, p.wo};
    do_transpose(tile, srcs[z], p.Wqkvg5t + (size_t)z * DIMc * DIMc, DIMc, DIMc, bxx, by, 0, t);
  } else if (bx < PR_T3) {
    int l = bx - PR_T2;
    int by = l / 192, bxx = l - by * 192;
    do_transpose(tile, p.tr_win, p.twint, DIMc, 2 * INNERc, bxx, by, 1, t);
  } else if (bx < PR_T4) {
    int l = bx - PR_T3;
    int by = l / 24, bxx = l - by * 24;
    do_transpose(tile, p.tr_wout, p.twoutt, INNERc, DIMc, bxx, by, 0, t);
  } else if (bx < PR_LN) {
    int row = bx - PR_T4;
    const float* x = p.cond + (size_t)row * DCONDc;
    float v0 = x[t], v1 = x[t + 256];
    float mean = block_sum(v0 + v1, red) * (1.0f / DCONDc);
    float d0 = v0 - mean, d1 = v1 - mean;
    float var = block_sum(d0 * d0 + d1 * d1, red) * (1.0f / DCONDc);
    float r = rsqrtf(var + 1e-5f);
    p.cnb[(size_t)row * DCONDc + t] = __float2bfloat16(d0 * r);
    p.cnb[(size_t)row * DCONDc + t + 256] = __float2bfloat16(d1 * r);
  } else if (bx < PR_CB) {
    int lb = bx - PR_LN;
    int i = lb * 256 + t;
    if (i < 6 * DIMc) {
      int seg = i / DIMc, o = i - seg * DIMc;
      float v = 0.f;
      if (seg == 0) v = p.a1_gb[o];
      else if (seg == 2) v = p.s1_b[o];
      else if (seg == 3) v = p.a2_gb[o];
      else if (seg == 5) v = p.s2_b[o];
      p.cb6[i] = v;
    }
    if (i < 4 * DIMc) {
      int seg = i / DIMc, o = i - seg * DIMc;
      p.bqkvg[i] = (seg == 0) ? p.bq[o] : (seg == 1) ? p.bk[o] : (seg == 2) ? p.bv[o] : p.bg[o];
    }
    if (i < 16 * DPAIRc) {
      int h = i >> 7, c = i & 127;
      p.wbT[i] = (h < Hc) ? __float2bfloat16(p.wb_pair[c * Hc + h]) : __float2bfloat16(0.f);
    }
    if (lb == 0 && t < 16) {
      int h = t;
      float s = 0.f;
      if (h < Hc)
        for (int c = 0; c < DPAIRc; ++c)
          s += __bfloat162float(__float2bfloat16(p.wb_pair[c * Hc + h]));
      p.colsum[h] = s;
    }
  } else {
    int idx = (bx - PR_CB) * 256 + t;   // 0..16383 = pos*32 + i
    int pos = idx >> 5, i = idx & 31;
    float ang = (float)pos * exp2f(-(float)i * 0.415241011861f);
    p.rope[idx * 2] = cosf(ang);
    p.rope[idx * 2 + 1] = sinf(ang);
  }
}

// ---------------- bf16 MFMA GEMM: C[M,N] = A[M,K] @ Bt[N,K]^T + epilogue -------
// global_load_lds width=16 staging + 2-phase double buffer (R2/R3 structure —
// counted-vmcnt variant measured slower here, reverted).
// mode 3: SiLU-pair epilogue (Bt rows interleaved a/g by 16) -> bf16 C, N/2 cols.
template <int WNT>
__global__ __launch_bounds__(256) void gemm_bf16_k(
    const __hip_bfloat16* __restrict__ A, const __hip_bfloat16* __restrict__ Bt,
    float* __restrict__ C, int M, int N, int K,
    const float* __restrict__ bias,
    const float* __restrict__ ss, int ssst,
    const float* __restrict__ resid, const float* __restrict__ maskp, int mode) {
  constexpr int TN = 32 * WNT;
  __shared__ __align__(16) __hip_bfloat16 As[2][128 * 32];
  __shared__ __align__(16) __hip_bfloat16 Bs[2][TN * 32];
  int tid = threadIdx.x;
  int lane = tid & 63, wv = tid >> 6;
  int l16 = lane & 15, quad = lane >> 4;
  int m0 = blockIdx.y * 128, n0 = blockIdx.x * TN;
  int wm0 = (wv >> 1) * 64, wn0 = (wv & 1) * (16 * WNT);

  int srow = tid >> 2;            // 0..63
  int skc = (tid & 3) * 8;        // bf16 column within 32-wide K-tile
  const __hip_bfloat16* Ab  = A  + (size_t)(m0 + srow) * K + skc;
  const __hip_bfloat16* Ab2 = Ab + (size_t)64 * K;
  const __hip_bfloat16* Bb  = Bt + (size_t)(n0 + srow) * K + skc;
  const __hip_bfloat16* Bb2 = Bb + (size_t)64 * K;
  __hip_bfloat16* AsW0 = &As[0][0] + wv * 512;   // wave-uniform LDS bases
  __hip_bfloat16* AsW1 = &As[1][0] + wv * 512;
  __hip_bfloat16* BsW0 = &Bs[0][0] + wv * 512;
  __hip_bfloat16* BsW1 = &Bs[1][0] + wv * 512;

  floatx4 acc[4][WNT];
#pragma unroll
  for (int mi = 0; mi < 4; ++mi)
#pragma unroll
    for (int nj = 0; nj < WNT; ++nj) acc[mi][nj] = (floatx4){0.f, 0.f, 0.f, 0.f};

  auto stage = [&](int kk, __hip_bfloat16* AW, __hip_bfloat16* BW) {
    gload16(Ab + kk, AW);
    gload16(Ab2 + kk, AW + 2048);
    if (WNT == 4) {
      gload16(Bb + kk, BW);
      gload16(Bb2 + kk, BW + 2048);
    } else {
      if (wv < 2) gload16(Bb + kk, BW);
    }
  };
  auto compute = [&](const __hip_bfloat16* Asb, const __hip_bfloat16* Bsb) {
    short8 a[4], b[WNT];
#pragma unroll
    for (int mi = 0; mi < 4; ++mi)
      a[mi] = *(const short8*)(const void*)&Asb[(wm0 + mi * 16 + l16) * 32 + quad * 8];
#pragma unroll
    for (int nj = 0; nj < WNT; ++nj)
      b[nj] = *(const short8*)(const void*)&Bsb[(wn0 + nj * 16 + l16) * 32 + quad * 8];
#pragma unroll
    for (int mi = 0; mi < 4; ++mi)
#pragma unroll
      for (int nj = 0; nj < WNT; ++nj)
        acc[mi][nj] = __builtin_amdgcn_mfma_f32_16x16x32_bf16(a[mi], b[nj], acc[mi][nj], 0, 0, 0);
  };

  // prologue
  stage(0, AsW0, BsW0);
  __syncthreads();
  for (int k0 = 0; k0 < K; k0 += 64) {
    if (k0 + 32 < K) stage(k0 + 32, AsW1, BsW1);
    compute(&As[0][0], &Bs[0][0]);
    __syncthreads();
    if (k0 + 64 < K) stage(k0 + 64, AsW0, BsW0);
    compute(&As[1][0], &Bs[1][0]);
    __syncthreads();
  }

  if (mode == 3) {
    if constexpr (WNT >= 2) {
      __hip_bfloat16* Cb = (__hip_bfloat16*)C;
      int halfN = N >> 1;
#pragma unroll
      for (int mi = 0; mi < 4; ++mi) {
#pragma unroll
        for (int njp = 0; njp < WNT / 2; ++njp) {
          int outcol = ((n0 + wn0) >> 1) + njp * 16 + l16;
#pragma unroll
          for (int r = 0; r < 4; ++r) {
            int m = m0 + wm0 + mi * 16 + quad * 4 + r;
            float av = acc[mi][2 * njp][r];
            float gv = acc[mi][2 * njp + 1][r];
            Cb[(size_t)m * halfN + outcol] = __float2bfloat16(av * gv * sigmoidf(gv));
          }
        }
      }
    }
    return;
  }

#pragma unroll
  for (int mi = 0; mi < 4; ++mi) {
#pragma unroll
    for (int nj = 0; nj < WNT; ++nj) {
      int ncol = n0 + wn0 + nj * 16 + l16;
      float bb = bias ? bias[ncol] : 0.f;
#pragma unroll
      for (int r = 0; r < 4; ++r) {
        int m = m0 + wm0 + mi * 16 + quad * 4 + r;
        float v = acc[mi][nj][r] + bb;
        if (mode == 1) {
          float mk = maskp[m];
          v *= sigmoidf(ss[(size_t)m * ssst + ncol]) * mk * mk;
          v = (v + resid[(size_t)m * N + ncol]) * mk;
        } else if (mode == 2) {
          float mk = maskp[m];
          v = v * mk * sigmoidf(ss[(size_t)m * ssst + ncol]) * mk * mk;
          v = (v + resid[(size_t)m * N + ncol]) * mk * mk;
        }
        C[(size_t)m * N + ncol] = v;
      }
    }
  }
}

// ---------------- adaLN apply (raw proj inputs, sigmoid fused) ----------------
__global__ __launch_bounds__(256) void adaln_apply_k(
    const float* __restrict__ xin, const float* __restrict__ maskp,
    const float* __restrict__ graw, const float* __restrict__ braw, int ssst,
    __hip_bfloat16* __restrict__ xa, float* __restrict__ xm) {
  __shared__ float red[4];
  int row = blockIdx.x;
  float mk = maskp[row];
  const float* xr = xin + (size_t)row * DIMc;
  float vals[3];
  float s = 0.f;
#pragma unroll
  for (int it = 0; it < 3; ++it) {
    int c = threadIdx.x + it * 256;
    float v = xr[c] * mk;
    vals[it] = v;
    s += v;
  }
  float mean = block_sum(s, red) * (1.0f / DIMc);
  float vs = 0.f;
#pragma unroll
  for (int it = 0; it < 3; ++it) { float d = vals[it] - mean; vs += d * d; }
  float var = block_sum(vs, red) * (1.0f / DIMc);
  float r = rsqrtf(var + 1e-5f);
#pragma unroll
  for (int it = 0; it < 3; ++it) {
    int c = threadIdx.x + it * 256;
    size_t sidx = (size_t)row * ssst + c;
    if (xm) xm[(size_t)row * DIMc + c] = vals[it];
    float o = ((vals[it] - mean) * r * sigmoidf(graw[sidx]) + braw[sidx]) * mk;
    xa[(size_t)row * DIMc + c] = __float2bfloat16(o);
  }
}

// ---------------- windowed pair bias via MFMA + post-LN fixup ----------------
__global__ __launch_bounds__(256) void pair_bias_mfma_k(
    const float* __restrict__ pr, const __hip_bfloat16* __restrict__ wbT,
    const float* __restrict__ colsum, float* __restrict__ biasw) {
  constexpr int LDR = 136;
  __shared__ __hip_bfloat16 rows[128 * LDR];
  __shared__ float meanS[128];
  __shared__ float rstdS[128];
  int bi = blockIdx.x;           // b*512 + i
  int i = bi & (Nc - 1), b = bi >> 9;
  int w = i >> 5, qi = i & 31;
  int j0 = w * NQc - 48;
  int t = threadIdx.x;
  int sub = t >> 5;
  int c4 = t & 31;
  const float* prb = pr + (size_t)bi * (Nc * DPAIRc);
#pragma unroll
  for (int step = 0; step < 16; ++step) {
    int row = step * 8 + sub;
    int jc = min(max(j0 + row, 0), Nc - 1);
    float4 v = *(const float4*)(prb + (size_t)jc * DPAIRc + c4 * 4);
    union { __hip_bfloat16 h[4]; uint2 u; } pk;
    pk.h[0] = __float2bfloat16(v.x); pk.h[1] = __float2bfloat16(v.y);
    pk.h[2] = __float2bfloat16(v.z); pk.h[3] = __float2bfloat16(v.w);
    *(uint2*)(void*)&rows[row * LDR + c4 * 4] = pk.u;
    float s = v.x + v.y + v.z + v.w;
    float s2 = v.x * v.x + v.y * v.y + v.z * v.z + v.w * v.w;
#pragma unroll
    for (int off = 16; off > 0; off >>= 1) {
      s += __shfl_xor(s, off, 64);
      s2 += __shfl_xor(s2, off, 64);
    }
    if (c4 == 0) {
      float mean = s * (1.0f / 128.0f);
      float var = s2 * (1.0f / 128.0f) - mean * mean;
      meanS[row] = mean;
      rstdS[row] = rsqrtf(var + 1e-5f);
    }
  }
  __syncthreads();
  int lane = t & 63, wv = t >> 6;
  int l16 = lane & 15, quad = lane >> 4;
  short8 bfrag[4];
#pragma unroll
  for (int ks = 0; ks < 4; ++ks)
    bfrag[ks] = *(const short8*)(const void*)&wbT[l16 * 128 + ks * 32 + quad * 8];
  float cs = colsum[l16];
#pragma unroll
  for (int mt = 0; mt < 2; ++mt) {
    int mtile = wv * 2 + mt;
    floatx4 acc = (floatx4){0.f, 0.f, 0.f, 0.f};
#pragma unroll
    for (int ks = 0; ks < 4; ++ks) {
      short8 a = *(const short8*)(const void*)&rows[(mtile * 16 + l16) * LDR + ks * 32 + quad * 8];
      acc = __builtin_amdgcn_mfma_f32_16x16x32_bf16(a, bfrag[ks], acc, 0, 0, 0);
    }
    if (l16 < Hc) {
      int m0r = mtile * 16 + quad * 4;
      float4 ov;
      float* po = &ov.x;
#pragma unroll
      for (int r = 0; r < 4; ++r) {
        int m = m0r + r;
        po[r] = rstdS[m] * (acc[r] - meanS[m] * cs);
      }
      *(float4*)&biasw[((((size_t)(b * Hc + l16)) * NWc + w) * NQc + qi) * NKc + m0r] = ov;
    }
  }
}

// ---------------- windowed attention: LN+RoPE(table) staging, MFMA QK^T/PV ----
__global__ __launch_bounds__(256) void wattn_k(
    const float* __restrict__ qkvg, const float* __restrict__ biasw,
    const float* __restrict__ pair_mask, const float* __restrict__ rope,
    __hip_bfloat16* __restrict__ o) {
  constexpr int LQ = 72;    // shorts per q/k row (64 + 8 pad)
  constexpr int LV = 136;   // shorts per vT row (128 keys + 8 pad)
  constexpr int LS = 132;   // floats per score row
  constexpr int LP = 136;   // shorts per P row
  __shared__ __hip_bfloat16 qs[32 * LQ];
  __shared__ __hip_bfloat16 ks[128 * LQ];
  __shared__ __hip_bfloat16 vT[64 * LV];
  __shared__ float sc[32 * LS];
  __shared__ __hip_bfloat16 scP[32 * LP];
  const int QS = 4 * DIMc;  // 3072
  int blk = blockIdx.x;     // (b*Hc + h)*NWc + w
  int w = blk & (NWc - 1);
  int bh = blk >> 4;
  int h = bh % Hc;
  int b = bh / Hc;
  int t = threadIdx.x;
  int j0 = w * NQc - 48;
  // stage q (bf16) with fused LN(64) + table RoPE.  16 lanes per row.
  for (int e = t; e < 512; e += 256) {
    int qrow = e >> 4, c4 = e & 15;
    float4 v = *(const float4*)&qkvg[(size_t)(b * Nc + w * NQc + qrow) * QS + h * DHc + c4 * 4];
    float s = v.x + v.y + v.z + v.w;
    float s2 = v.x * v.x + v.y * v.y + v.z * v.z + v.w * v.w;
#pragma unroll
    for (int off = 1; off < 16; off <<= 1) {
      s += __shfl_xor(s, off, 64);
      s2 += __shfl_xor(s2, off, 64);
    }
    float mean = s * (1.0f / 64.0f);
    float rr = rsqrtf(s2 * (1.0f / 64.0f) - mean * mean + 1e-5f);
    float qn0 = (v.x - mean) * rr, qn1 = (v.y - mean) * rr;
    float qn2 = (v.z - mean) * rr, qn3 = (v.w - mean) * rr;
    float4 cs4 = *(const float4*)&rope[(size_t)(w * NQc + qrow) * 64 + c4 * 4];
    union { __hip_bfloat16 hh[4]; uint2 u; } pk;
    pk.hh[0] = __float2bfloat16(qn0 * cs4.x - qn1 * cs4.y);
    pk.hh[1] = __float2bfloat16(qn0 * cs4.y + qn1 * cs4.x);
    pk.hh[2] = __float2bfloat16(qn2 * cs4.z - qn3 * cs4.w);
    pk.hh[3] = __float2bfloat16(qn2 * cs4.w + qn3 * cs4.z);
    *(uint2*)(void*)&qs[qrow * LQ + c4 * 4] = pk.u;
  }
  // stage k (fused LN + table RoPE, row-major) and v (raw, transposed)
  for (int e = t; e < 2048; e += 256) {
    int kk = e >> 4, c4 = e & 15;
    int jc = min(max(j0 + kk, 0), Nc - 1);
    size_t src = (size_t)(b * Nc + jc) * QS + h * DHc + c4 * 4;
    float4 kv = *(const float4*)&qkvg[src + DIMc];
    float4 vv = *(const float4*)&qkvg[src + 2 * DIMc];
    float s = kv.x + kv.y + kv.z + kv.w;
    float s2 = kv.x * kv.x + kv.y * kv.y + kv.z * kv.z + kv.w * kv.w;
#pragma unroll
    for (int off = 1; off < 16; off <<= 1) {
      s += __shfl_xor(s, off, 64);
      s2 += __shfl_xor(s2, off, 64);
    }
    float mean = s * (1.0f / 64.0f);
    float rr = rsqrtf(s2 * (1.0f / 64.0f) - mean * mean + 1e-5f);
    float kn0 = (kv.x - mean) * rr, kn1 = (kv.y - mean) * rr;
    float kn2 = (kv.z - mean) * rr, kn3 = (kv.w - mean) * rr;
    float4 cs4 = *(const float4*)&rope[(size_t)jc * 64 + c4 * 4];
    union { __hip_bfloat16 hh[4]; uint2 u; } pk;
    pk.hh[0] = __float2bfloat16(kn0 * cs4.x - kn1 * cs4.y);
    pk.hh[1] = __float2bfloat16(kn0 * cs4.y + kn1 * cs4.x);
    pk.hh[2] = __float2bfloat16(kn2 * cs4.z - kn3 * cs4.w);
    pk.hh[3] = __float2bfloat16(kn2 * cs4.w + kn3 * cs4.z);
    *(uint2*)(void*)&ks[kk * LQ + c4 * 4] = pk.u;
    vT[(c4 * 4 + 0) * LV + kk] = __float2bfloat16(vv.x);
    vT[(c4 * 4 + 1) * LV + kk] = __float2bfloat16(vv.y);
    vT[(c4 * 4 + 2) * LV + kk] = __float2bfloat16(vv.z);
    vT[(c4 * 4 + 3) * LV + kk] = __float2bfloat16(vv.w);
  }
  // pre-fill score buffer with bias or -inf (mask/validity)
  for (int e = t; e < 4096; e += 256) {
    int qrow = e >> 7, key = e & 127;
    int j = j0 + key;
    bool valid = (j >= 0) && (j < Nc);
    int jc = min(max(j, 0), Nc - 1);
    float pm = pair_mask[((size_t)(b * Nc + w * NQc + qrow)) * Nc + jc];
    bool ok = valid && (pm > 0.f);
    sc[qrow * LS + key] = ok ? biasw[((size_t)blk * 32 + qrow) * 128 + key] : -1e30f;
  }
  __syncthreads();
  int lane = t & 63, wv = t >> 6;
  int l16 = lane & 15, quad = lane >> 4;
  // QK^T: wave wv handles keys [wv*32, wv*32+32), both m-tiles
  {
    short8 bfr[2][2];
#pragma unroll
    for (int nt = 0; nt < 2; ++nt)
#pragma unroll
      for (int k2 = 0; k2 < 2; ++k2)
        bfr[nt][k2] = *(const short8*)(const void*)&ks[(wv * 32 + nt * 16 + l16) * LQ + k2 * 32 + quad * 8];
#pragma unroll
    for (int mi = 0; mi < 2; ++mi) {
      short8 afr[2];
#pragma unroll
      for (int k2 = 0; k2 < 2; ++k2)
        afr[k2] = *(const short8*)(const void*)&qs[(mi * 16 + l16) * LQ + k2 * 32 + quad * 8];
#pragma unroll
      for (int nt = 0; nt < 2; ++nt) {
        floatx4 acc = (floatx4){0.f, 0.f, 0.f, 0.f};
        acc = __builtin_amdgcn_mfma_f32_16x16x32_bf16(afr[0], bfr[nt][0], acc, 0, 0, 0);
        acc = __builtin_amdgcn_mfma_f32_16x16x32_bf16(afr[1], bfr[nt][1], acc, 0, 0, 0);
        int key = wv * 32 + nt * 16 + l16;
#pragma unroll
        for (int r = 0; r < 4; ++r) {
          int m = mi * 16 + quad * 4 + r;
          float sv = sc[m * LS + key];
          if (sv > -1e29f) sc[m * LS + key] = sv + acc[r] * 0.125f;
        }
      }
    }
  }
  __syncthreads();
  // softmax: wave per 8 rows, write P as bf16
#pragma unroll
  for (int rr = 0; rr < 8; ++rr) {
    int qq = wv * 8 + rr;
    float v0 = sc[qq * LS + lane], v1 = sc[qq * LS + 64 + lane];
    float mx = wave_max(fmaxf(v0, v1));
    float e0 = expf(v0 - mx), e1 = expf(v1 - mx);
    float inv = 1.0f / wave_sum(e0 + e1);
    scP[qq * LP + lane] = __float2bfloat16(e0 * inv);
    scP[qq * LP + 64 + lane] = __float2bfloat16(e1 * inv);
  }
  __syncthreads();
  // PV: wave wv handles d-range [wv*16, wv*16+16), both m-tiles
  {
    short8 vb[4];
#pragma unroll
    for (int k4 = 0; k4 < 4; ++k4)
      vb[k4] = *(const short8*)(const void*)&vT[(wv * 16 + l16) * LV + k4 * 32 + quad * 8];
#pragma unroll
    for (int mi = 0; mi < 2; ++mi) {
      floatx4 acc = (floatx4){0.f, 0.f, 0.f, 0.f};
#pragma unroll
      for (int k4 = 0; k4 < 4; ++k4) {
        short8 pa = *(const short8*)(const void*)&scP[(mi * 16 + l16) * LP + k4 * 32 + quad * 8];
        acc = __builtin_amdgcn_mfma_f32_16x16x32_bf16(pa, vb[k4], acc, 0, 0, 0);
      }
      int d = wv * 16 + l16;
#pragma unroll
      for (int r = 0; r < 4; ++r) {
        int m = mi * 16 + quad * 4 + r;
        size_t mrow = (size_t)(b * Nc + w * NQc + m);
        float g = qkvg[mrow * QS + 3 * DIMc + h * DHc + d];
        o[mrow * DIMc + h * DHc + d] = __float2bfloat16(acc[r] * sigmoidf(g));
      }
    }
  }
}

extern "C" void kernel_launch(void* const* d_in, const int* in_sizes, int n_in,
                              void* d_out, int out_size, void* d_ws, size_t ws_size,
                              hipStream_t stream) {
  const float* x        = (const float*)d_in[0];
  const float* pair_rep = (const float*)d_in[1];
  const float* cond     = (const float*)d_in[2];
  const float* mask     = (const float*)d_in[3];
  const float* pair_mask= (const float*)d_in[4];
  const float* a1_gw    = (const float*)d_in[5];
  const float* a1_gb    = (const float*)d_in[6];
  const float* a1_bw    = (const float*)d_in[7];
  const float* wq       = (const float*)d_in[8];
  const float* bq       = (const float*)d_in[9];
  const float* wk       = (const float*)d_in[10];
  const float* bk       = (const float*)d_in[11];
  const float* wv       = (const float*)d_in[12];
  const float* bv       = (const float*)d_in[13];
  const float* wg       = (const float*)d_in[14];
  const float* bg       = (const float*)d_in[15];
  const float* wb_pair  = (const float*)d_in[16];
  const float* wo       = (const float*)d_in[17];
  const float* bo       = (const float*)d_in[18];
  const float* s1_w     = (const float*)d_in[19];
  const float* s1_b     = (const float*)d_in[20];
  const float* a2_gw    = (const float*)d_in[21];
  const float* a2_gb    = (const float*)d_in[22];
  const float* a2_bw    = (const float*)d_in[23];
  const float* tr_win   = (const float*)d_in[24];
  const float* tr_wout  = (const float*)d_in[25];
  const float* s2_w     = (const float*)d_in[26];
  const float* s2_b     = (const float*)d_in[27];
  float* out = (float*)d_out;

  const int M = Bc * Nc;  // 1024
  char* wsb = (char*)d_ws;
  size_t off = 0;
  auto alloc = [&](size_t bytes) { void* p = wsb + off; off += (bytes + 255) & ~(size_t)255; return p; };

  __hip_bfloat16* cnb     = (__hip_bfloat16*)alloc((size_t)M * DCONDc * 2);
  __hip_bfloat16* Wc6t    = (__hip_bfloat16*)alloc((size_t)6 * DIMc * DCONDc * 2);
  __hip_bfloat16* Wqkvg5t = (__hip_bfloat16*)alloc((size_t)5 * DIMc * DIMc * 2);
  __hip_bfloat16* twint   = (__hip_bfloat16*)alloc((size_t)2 * INNERc * DIMc * 2);
  __hip_bfloat16* twoutt  = (__hip_bfloat16*)alloc((size_t)DIMc * INNERc * 2);
  float* cb6    = (float*)alloc((size_t)6 * DIMc * 4);
  float* bqkvg  = (float*)alloc((size_t)4 * DIMc * 4);
  __hip_bfloat16* wbT = (__hip_bfloat16*)alloc((size_t)16 * DPAIRc * 2);
  float* colsum = (float*)alloc(16 * 4);
  float* rope   = (float*)alloc((size_t)Nc * 64 * 4);   // [pos][i](cos,sin)
  float* proj_c = (float*)alloc((size_t)M * 6 * DIMc * 4);
  float* xm     = (float*)alloc((size_t)M * DIMc * 4);
  __hip_bfloat16* xa = (__hip_bfloat16*)alloc((size_t)M * DIMc * 2);
  float* qkvg   = (float*)alloc((size_t)M * 4 * DIMc * 4);
  float* biasw  = (float*)alloc((size_t)Bc * Hc * NWc * NQc * NKc * 4);
  __hip_bfloat16* obg = (__hip_bfloat16*)alloc((size_t)M * DIMc * 2);
  float* x2     = (float*)alloc((size_t)M * DIMc * 4);
  __hip_bfloat16* xt = (__hip_bfloat16*)alloc((size_t)M * DIMc * 2);
  __hip_bfloat16* actb = (__hip_bfloat16*)alloc((size_t)M * INNERc * 2);
  __hip_bfloat16* wot = Wqkvg5t + (size_t)4 * DIMc * DIMc;
  (void)ws_size; (void)in_sizes; (void)n_in; (void)out_size;

  dim3 blk(256);

  PrepArgs pa;
  pa.a1_gw = a1_gw; pa.a1_bw = a1_bw; pa.s1_w = s1_w;
  pa.a2_gw = a2_gw; pa.a2_bw = a2_bw; pa.s2_w = s2_w;
  pa.wq = wq; pa.wk = wk; pa.wv = wv; pa.wg = wg; pa.wo = wo;
  pa.tr_win = tr_win; pa.tr_wout = tr_wout;
  pa.cond = cond;
  pa.a1_gb = a1_gb; pa.s1_b = s1_b; pa.a2_gb = a2_gb; pa.s2_b = s2_b;
  pa.bq = bq; pa.bk = bk; pa.bv = bv; pa.bg = bg; pa.wb_pair = wb_pair;
  pa.Wc6t = Wc6t; pa.Wqkvg5t = Wqkvg5t; pa.twint = twint; pa.twoutt = twoutt;
  pa.cnb = cnb; pa.wbT = wbT;
  pa.cb6 = cb6; pa.bqkvg = bqkvg; pa.colsum = colsum; pa.rope = rope;
  prep_k<<<PR_RT, blk, 0, stream>>>(pa);

  gemm_bf16_k<4><<<dim3(6 * DIMc / 128, M / 128), blk, 0, stream>>>(
      cnb, Wc6t, proj_c, M, 6 * DIMc, DCONDc, cb6, nullptr, 0, nullptr, nullptr, 0);

  adaln_apply_k<<<M, blk, 0, stream>>>(x, mask, proj_c + 0, proj_c + DIMc, 6 * DIMc, xa, xm);

  gemm_bf16_k<4><<<dim3(4 * DIMc / 128, M / 128), blk, 0, stream>>>(
      xa, Wqkvg5t, qkvg, M, 4 * DIMc, DIMc, bqkvg, nullptr, 0, nullptr, nullptr, 0);

  pair_bias_mfma_k<<<Bc * Nc, blk, 0, stream>>>(pair_rep, wbT, colsum, biasw);

  wattn_k<<<Bc * Hc * NWc, blk, 0, stream>>>(qkvg, biasw, pair_mask, rope, obg);

  gemm_bf16_k<1><<<dim3(DIMc / 32, M / 128), blk, 0, stream>>>(
      obg, wot, x2, M, DIMc, DIMc, bo, proj_c + 2 * DIMc, 6 * DIMc, xm, mask, 1);

  adaln_apply_k<<<M, blk, 0, stream>>>(x2, mask, proj_c + 3 * DIMc, proj_c + 4 * DIMc,
                                       6 * DIMc, xt, nullptr);

  gemm_bf16_k<4><<<dim3(2 * INNERc / 128, M / 128), blk, 0, stream>>>(
      xt, twint, (float*)actb, M, 2 * INNERc, DIMc, nullptr, nullptr, 0, nullptr, nullptr, 3);

  gemm_bf16_k<1><<<dim3(DIMc / 32, M / 128), blk, 0, stream>>>(
      actb, twoutt, out, M, DIMc, INNERc, nullptr, proj_c + 5 * DIMc, 6 * DIMc, x2, mask, 2);
}

// Round 6
// 539.005 us; speedup vs baseline: 1.1114x; 1.0542x over previous
//
#include <hip/hip_runtime.h>
#include <hip/hip_bf16.h>
#include <math.h>
#include <stdint.h>

// Problem constants
#define Bc   2
#define Nc   512
#define Hc   12
#define DHc  64
#define DIMc 768
#define DPAIRc 128
#define DCONDc 512
#define INNERc 3072
#define NQc  32
#define NKc  128
#define NWc  (Nc / NQc)   // 16

typedef __attribute__((ext_vector_type(8))) short short8;
typedef __attribute__((ext_vector_type(4))) float floatx4;

// ---------------- helpers ----------------
__device__ inline float wave_sum(float v) {
#pragma unroll
  for (int off = 32; off > 0; off >>= 1) v += __shfl_xor(v, off, 64);
  return v;
}
__device__ inline float wave_max(float v) {
#pragma unroll
  for (int off = 32; off > 0; off >>= 1) v = fmaxf(v, __shfl_xor(v, off, 64));
  return v;
}
__device__ inline float block_sum(float v, float* red) {
  v = wave_sum(v);
  int wv = threadIdx.x >> 6, lane = threadIdx.x & 63;
  __syncthreads();
  if (lane == 0) red[wv] = v;
  __syncthreads();
  return red[0] + red[1] + red[2] + red[3];
}
__device__ inline float sigmoidf(float x) { return 1.0f / (1.0f + expf(-x)); }

// async global->LDS 16B DMA. LDS dest is wave-uniform base + lane*16 (m104).
__device__ __forceinline__ void gload16(const void* g, void* l) {
  __builtin_amdgcn_global_load_lds(
      reinterpret_cast<__attribute__((address_space(1))) const void*>(
          reinterpret_cast<uintptr_t>(g)),
      reinterpret_cast<__attribute__((address_space(3))) void*>(
          static_cast<uint32_t>(reinterpret_cast<uintptr_t>(l))),
      16, 0, 0);
}

// ---------------- fused prep kernel -------------------------------------------
struct PrepArgs {
  const float *a1_gw, *a1_bw, *s1_w, *a2_gw, *a2_bw, *s2_w;
  const float *wq, *wk, *wv, *wg, *wo;
  const float *tr_win, *tr_wout;
  const float *cond;
  const float *a1_gb, *s1_b, *a2_gb, *s2_b;
  const float *bq, *bk, *bv, *bg, *wb_pair;
  __hip_bfloat16 *Wc6t, *Wqkvg5t, *twint, *twoutt, *cnb, *wbT;
  float *cb6, *bqkvg, *colsum, *rope;
};

#define PR_T1 2304                 // Wc6t tiles   (24 x 16 x 6)
#define PR_T2 (PR_T1 + 2880)       // Wqkvg5t      (24 x 24 x 5)
#define PR_T3 (PR_T2 + 4608)       // twint        (192 x 24), interleaved
#define PR_T4 (PR_T3 + 2304)       // twoutt       (24 x 96)
#define PR_LN (PR_T4 + 1024)       // ln_rows cond
#define PR_CB (PR_LN + 18)         // concat bias
#define PR_RT (PR_CB + 64)         // rope table (512 x 32)

__device__ __forceinline__ void do_transpose(float (*tile)[33], const float* __restrict__ src,
    __hip_bfloat16* __restrict__ dst, int K, int N, int bxx, int byy, int interleave, int t) {
  int k0 = byy * 32, n0 = bxx * 32;
  int r = t >> 5, c = t & 31;
#pragma unroll
  for (int i = 0; i < 4; ++i) tile[r + i * 8][c] = src[(size_t)(k0 + r + i * 8) * N + n0 + c];
  __syncthreads();
#pragma unroll
  for (int i = 0; i < 4; ++i) {
    int n = n0 + r + i * 8;
    int dr = n;
    if (interleave) {
      int half = N >> 1;
      dr = (n < half) ? (((n >> 4) << 5) + (n & 15))
                      : ((((n - half) >> 4) << 5) + 16 + ((n - half) & 15));
    }
    dst[(size_t)dr * K + k0 + c] = __float2bfloat16(tile[c][r + i * 8]);
  }
}

__global__ __launch_bounds__(256) void prep_k(PrepArgs p) {
  __shared__ float tile[32][33];
  __shared__ float red[4];
  int bx = blockIdx.x, t = threadIdx.x;
  if (bx < PR_T1) {
    int z = bx / 384, rem = bx - z * 384;
    int by = rem / 24, bxx = rem - by * 24;
    const float* srcs[6] = {p.a1_gw, p.a1_bw, p.s1_w, p.a2_gw, p.a2_bw, p.s2_w};
    do_transpose(tile, srcs[z], p.Wc6t + (size_t)z * DIMc * DCONDc, DCONDc, DIMc, bxx, by, 0, t);
  } else if (bx < PR_T2) {
    int l = bx - PR_T1;
    int z = l / 576, rem = l - z * 576;
    int by = rem / 24, bxx = rem - by * 24;
    const float* srcs[5] = {p.wq, p.wk, p.wv, p.wg, p.wo};
    do_transpose(tile, srcs[z], p.Wqkvg5t + (size_t)z * DIMc * DIMc, DIMc, DIMc, bxx, by, 0, t);
  } else if (bx < PR_T3) {
    int l = bx - PR_T2;
    int by = l / 192, bxx = l - by * 192;
    do_transpose(tile, p.tr_win, p.twint, DIMc, 2 * INNERc, bxx, by, 1, t);
  } else if (bx < PR_T4) {
    int l = bx - PR_T3;
    int by = l / 24, bxx = l - by * 24;
    do_transpose(tile, p.tr_wout, p.twoutt, INNERc, DIMc, bxx, by, 0, t);
  } else if (bx < PR_LN) {
    int row = bx - PR_T4;
    const float* x = p.cond + (size_t)row * DCONDc;
    float v0 = x[t], v1 = x[t + 256];
    float mean = block_sum(v0 + v1, red) * (1.0f / DCONDc);
    float d0 = v0 - mean, d1 = v1 - mean;
    float var = block_sum(d0 * d0 + d1 * d1, red) * (1.0f / DCONDc);
    float r = rsqrtf(var + 1e-5f);
    p.cnb[(size_t)row * DCONDc + t] = __float2bfloat16(d0 * r);
    p.cnb[(size_t)row * DCONDc + t + 256] = __float2bfloat16(d1 * r);
  } else if (bx < PR_CB) {
    int lb = bx - PR_LN;
    int i = lb * 256 + t;
    if (i < 6 * DIMc) {
      int seg = i / DIMc, o = i - seg * DIMc;
      float v = 0.f;
      if (seg == 0) v = p.a1_gb[o];
      else if (seg == 2) v = p.s1_b[o];
      else if (seg == 3) v = p.a2_gb[o];
      else if (seg == 5) v = p.s2_b[o];
      p.cb6[i] = v;
    }
    if (i < 4 * DIMc) {
      int seg = i / DIMc, o = i - seg * DIMc;
      p.bqkvg[i] = (seg == 0) ? p.bq[o] : (seg == 1) ? p.bk[o] : (seg == 2) ? p.bv[o] : p.bg[o];
    }
    if (i < 16 * DPAIRc) {
      int h = i >> 7, c = i & 127;
      p.wbT[i] = (h < Hc) ? __float2bfloat16(p.wb_pair[c * Hc + h]) : __float2bfloat16(0.f);
    }
    if (lb == 0 && t < 16) {
      int h = t;
      float s = 0.f;
      if (h < Hc)
        for (int c = 0; c < DPAIRc; ++c)
          s += __bfloat162float(__float2bfloat16(p.wb_pair[c * Hc + h]));
      p.colsum[h] = s;
    }
  } else {
    int idx = (bx - PR_CB) * 256 + t;   // 0..16383 = pos*32 + i
    int pos = idx >> 5, i = idx & 31;
    float ang = (float)pos * exp2f(-(float)i * 0.415241011861f);
    p.rope[idx * 2] = cosf(ang);
    p.rope[idx * 2 + 1] = sinf(ang);
  }
}

// ---------------- bf16 MFMA GEMM: C[M,N] = A[M,K] @ Bt[N,K]^T + epilogue -------
// BM=64 tiles (2x grid vs BM=128) for >=2 co-resident blocks/CU: unsynchronized
// blocks hide each other's barrier/load stalls (m114). global_load_lds staging
// + 2-phase double buffer. Wave layout 2x2: 32 rows x TN/2 cols per wave.
// mode 3: SiLU-pair epilogue (Bt rows interleaved a/g by 16) -> bf16 C, N/2 cols.
template <int WNT>
__global__ __launch_bounds__(256) void gemm_bf16_k(
    const __hip_bfloat16* __restrict__ A, const __hip_bfloat16* __restrict__ Bt,
    float* __restrict__ C, int M, int N, int K,
    const float* __restrict__ bias,
    const float* __restrict__ ss, int ssst,
    const float* __restrict__ resid, const float* __restrict__ maskp, int mode) {
  constexpr int TN = 32 * WNT;
  __shared__ __align__(16) __hip_bfloat16 As[2][64 * 32];
  __shared__ __align__(16) __hip_bfloat16 Bs[2][TN * 32];
  int tid = threadIdx.x;
  int lane = tid & 63, wv = tid >> 6;
  int l16 = lane & 15, quad = lane >> 4;
  int m0 = blockIdx.y * 64, n0 = blockIdx.x * TN;
  int wm0 = (wv >> 1) * 32, wn0 = (wv & 1) * (16 * WNT);

  int srow = tid >> 2;            // 0..63
  int skc = (tid & 3) * 8;        // bf16 column within 32-wide K-tile
  const __hip_bfloat16* Ab  = A  + (size_t)(m0 + srow) * K + skc;
  const __hip_bfloat16* Bb  = Bt + (size_t)(n0 + srow) * K + skc;
  const __hip_bfloat16* Bb2 = Bb + (size_t)64 * K;
  __hip_bfloat16* AsW0 = &As[0][0] + wv * 512;   // wave-uniform LDS bases
  __hip_bfloat16* AsW1 = &As[1][0] + wv * 512;
  __hip_bfloat16* BsW0 = &Bs[0][0] + wv * 512;
  __hip_bfloat16* BsW1 = &Bs[1][0] + wv * 512;

  floatx4 acc[2][WNT];
#pragma unroll
  for (int mi = 0; mi < 2; ++mi)
#pragma unroll
    for (int nj = 0; nj < WNT; ++nj) acc[mi][nj] = (floatx4){0.f, 0.f, 0.f, 0.f};

  auto stage = [&](int kk, __hip_bfloat16* AW, __hip_bfloat16* BW) {
    gload16(Ab + kk, AW);                 // A: 64x32 = 256 slots, 1 round
    if (WNT == 4) {
      gload16(Bb + kk, BW);               // B: 128x32 = 512 slots, 2 rounds
      gload16(Bb2 + kk, BW + 2048);
    } else {
      if (wv < 2) gload16(Bb + kk, BW);   // B: 32x32 = 128 slots
    }
  };
  auto compute = [&](const __hip_bfloat16* Asb, const __hip_bfloat16* Bsb) {
    short8 a[2], b[WNT];
#pragma unroll
    for (int mi = 0; mi < 2; ++mi)
      a[mi] = *(const short8*)(const void*)&Asb[(wm0 + mi * 16 + l16) * 32 + quad * 8];
#pragma unroll
    for (int nj = 0; nj < WNT; ++nj)
      b[nj] = *(const short8*)(const void*)&Bsb[(wn0 + nj * 16 + l16) * 32 + quad * 8];
#pragma unroll
    for (int mi = 0; mi < 2; ++mi)
#pragma unroll
      for (int nj = 0; nj < WNT; ++nj)
        acc[mi][nj] = __builtin_amdgcn_mfma_f32_16x16x32_bf16(a[mi], b[nj], acc[mi][nj], 0, 0, 0);
  };

  // prologue
  stage(0, AsW0, BsW0);
  __syncthreads();
  for (int k0 = 0; k0 < K; k0 += 64) {
    if (k0 + 32 < K) stage(k0 + 32, AsW1, BsW1);
    compute(&As[0][0], &Bs[0][0]);
    __syncthreads();
    if (k0 + 64 < K) stage(k0 + 64, AsW0, BsW0);
    compute(&As[1][0], &Bs[1][0]);
    __syncthreads();
  }

  if (mode == 3) {
    if constexpr (WNT >= 2) {
      __hip_bfloat16* Cb = (__hip_bfloat16*)C;
      int halfN = N >> 1;
#pragma unroll
      for (int mi = 0; mi < 2; ++mi) {
#pragma unroll
        for (int njp = 0; njp < WNT / 2; ++njp) {
          int outcol = ((n0 + wn0) >> 1) + njp * 16 + l16;
#pragma unroll
          for (int r = 0; r < 4; ++r) {
            int m = m0 + wm0 + mi * 16 + quad * 4 + r;
            float av = acc[mi][2 * njp][r];
            float gv = acc[mi][2 * njp + 1][r];
            Cb[(size_t)m * halfN + outcol] = __float2bfloat16(av * gv * sigmoidf(gv));
          }
        }
      }
    }
    return;
  }

#pragma unroll
  for (int mi = 0; mi < 2; ++mi) {
#pragma unroll
    for (int nj = 0; nj < WNT; ++nj) {
      int ncol = n0 + wn0 + nj * 16 + l16;
      float bb = bias ? bias[ncol] : 0.f;
#pragma unroll
      for (int r = 0; r < 4; ++r) {
        int m = m0 + wm0 + mi * 16 + quad * 4 + r;
        float v = acc[mi][nj][r] + bb;
        if (mode == 1) {
          float mk = maskp[m];
          v *= sigmoidf(ss[(size_t)m * ssst + ncol]) * mk * mk;
          v = (v + resid[(size_t)m * N + ncol]) * mk;
        } else if (mode == 2) {
          float mk = maskp[m];
          v = v * mk * sigmoidf(ss[(size_t)m * ssst + ncol]) * mk * mk;
          v = (v + resid[(size_t)m * N + ncol]) * mk * mk;
        }
        C[(size_t)m * N + ncol] = v;
      }
    }
  }
}

// ---------------- adaLN apply (raw proj inputs, sigmoid fused) ----------------
__global__ __launch_bounds__(256) void adaln_apply_k(
    const float* __restrict__ xin, const float* __restrict__ maskp,
    const float* __restrict__ graw, const float* __restrict__ braw, int ssst,
    __hip_bfloat16* __restrict__ xa, float* __restrict__ xm) {
  __shared__ float red[4];
  int row = blockIdx.x;
  float mk = maskp[row];
  const float* xr = xin + (size_t)row * DIMc;
  float vals[3];
  float s = 0.f;
#pragma unroll
  for (int it = 0; it < 3; ++it) {
    int c = threadIdx.x + it * 256;
    float v = xr[c] * mk;
    vals[it] = v;
    s += v;
  }
  float mean = block_sum(s, red) * (1.0f / DIMc);
  float vs = 0.f;
#pragma unroll
  for (int it = 0; it < 3; ++it) { float d = vals[it] - mean; vs += d * d; }
  float var = block_sum(vs, red) * (1.0f / DIMc);
  float r = rsqrtf(var + 1e-5f);
#pragma unroll
  for (int it = 0; it < 3; ++it) {
    int c = threadIdx.x + it * 256;
    size_t sidx = (size_t)row * ssst + c;
    if (xm) xm[(size_t)row * DIMc + c] = vals[it];
    float o = ((vals[it] - mean) * r * sigmoidf(graw[sidx]) + braw[sidx]) * mk;
    xa[(size_t)row * DIMc + c] = __float2bfloat16(o);
  }
}

// ---------------- windowed pair bias via MFMA + post-LN fixup ----------------
__global__ __launch_bounds__(256) void pair_bias_mfma_k(
    const float* __restrict__ pr, const __hip_bfloat16* __restrict__ wbT,
    const float* __restrict__ colsum, float* __restrict__ biasw) {
  constexpr int LDR = 136;
  __shared__ __hip_bfloat16 rows[128 * LDR];
  __shared__ float meanS[128];
  __shared__ float rstdS[128];
  int bi = blockIdx.x;           // b*512 + i
  int i = bi & (Nc - 1), b = bi >> 9;
  int w = i >> 5, qi = i & 31;
  int j0 = w * NQc - 48;
  int t = threadIdx.x;
  int sub = t >> 5;
  int c4 = t & 31;
  const float* prb = pr + (size_t)bi * (Nc * DPAIRc);
#pragma unroll
  for (int step = 0; step < 16; ++step) {
    int row = step * 8 + sub;
    int jc = min(max(j0 + row, 0), Nc - 1);
    float4 v = *(const float4*)(prb + (size_t)jc * DPAIRc + c4 * 4);
    union { __hip_bfloat16 h[4]; uint2 u; } pk;
    pk.h[0] = __float2bfloat16(v.x); pk.h[1] = __float2bfloat16(v.y);
    pk.h[2] = __float2bfloat16(v.z); pk.h[3] = __float2bfloat16(v.w);
    *(uint2*)(void*)&rows[row * LDR + c4 * 4] = pk.u;
    float s = v.x + v.y + v.z + v.w;
    float s2 = v.x * v.x + v.y * v.y + v.z * v.z + v.w * v.w;
#pragma unroll
    for (int off = 16; off > 0; off >>= 1) {
      s += __shfl_xor(s, off, 64);
      s2 += __shfl_xor(s2, off, 64);
    }
    if (c4 == 0) {
      float mean = s * (1.0f / 128.0f);
      float var = s2 * (1.0f / 128.0f) - mean * mean;
      meanS[row] = mean;
      rstdS[row] = rsqrtf(var + 1e-5f);
    }
  }
  __syncthreads();
  int lane = t & 63, wv = t >> 6;
  int l16 = lane & 15, quad = lane >> 4;
  short8 bfrag[4];
#pragma unroll
  for (int ks = 0; ks < 4; ++ks)
    bfrag[ks] = *(const short8*)(const void*)&wbT[l16 * 128 + ks * 32 + quad * 8];
  float cs = colsum[l16];
#pragma unroll
  for (int mt = 0; mt < 2; ++mt) {
    int mtile = wv * 2 + mt;
    floatx4 acc = (floatx4){0.f, 0.f, 0.f, 0.f};
#pragma unroll
    for (int ks = 0; ks < 4; ++ks) {
      short8 a = *(const short8*)(const void*)&rows[(mtile * 16 + l16) * LDR + ks * 32 + quad * 8];
      acc = __builtin_amdgcn_mfma_f32_16x16x32_bf16(a, bfrag[ks], acc, 0, 0, 0);
    }
    if (l16 < Hc) {
      int m0r = mtile * 16 + quad * 4;
      float4 ov;
      float* po = &ov.x;
#pragma unroll
      for (int r = 0; r < 4; ++r) {
        int m = m0r + r;
        po[r] = rstdS[m] * (acc[r] - meanS[m] * cs);
      }
      *(float4*)&biasw[((((size_t)(b * Hc + l16)) * NWc + w) * NQc + qi) * NKc + m0r] = ov;
    }
  }
}

// ---------------- windowed attention: LN+RoPE(table) staging, MFMA QK^T/PV ----
__global__ __launch_bounds__(256) void wattn_k(
    const float* __restrict__ qkvg, const float* __restrict__ biasw,
    const float* __restrict__ pair_mask, const float* __restrict__ rope,
    __hip_bfloat16* __restrict__ o) {
  constexpr int LQ = 72;    // shorts per q/k row (64 + 8 pad)
  constexpr int LV = 136;   // shorts per vT row (128 keys + 8 pad)
  constexpr int LS = 132;   // floats per score row
  constexpr int LP = 136;   // shorts per P row
  __shared__ __hip_bfloat16 qs[32 * LQ];
  __shared__ __hip_bfloat16 ks[128 * LQ];
  __shared__ __hip_bfloat16 vT[64 * LV];
  __shared__ float sc[32 * LS];
  __shared__ __hip_bfloat16 scP[32 * LP];
  const int QS = 4 * DIMc;  // 3072
  int blk = blockIdx.x;     // (b*Hc + h)*NWc + w
  int w = blk & (NWc - 1);
  int bh = blk >> 4;
  int h = bh % Hc;
  int b = bh / Hc;
  int t = threadIdx.x;
  int j0 = w * NQc - 48;
  // stage q (bf16) with fused LN(64) + table RoPE.  16 lanes per row.
  for (int e = t; e < 512; e += 256) {
    int qrow = e >> 4, c4 = e & 15;
    float4 v = *(const float4*)&qkvg[(size_t)(b * Nc + w * NQc + qrow) * QS + h * DHc + c4 * 4];
    float s = v.x + v.y + v.z + v.w;
    float s2 = v.x * v.x + v.y * v.y + v.z * v.z + v.w * v.w;
#pragma unroll
    for (int off = 1; off < 16; off <<= 1) {
      s += __shfl_xor(s, off, 64);
      s2 += __shfl_xor(s2, off, 64);
    }
    float mean = s * (1.0f / 64.0f);
    float rr = rsqrtf(s2 * (1.0f / 64.0f) - mean * mean + 1e-5f);
    float qn0 = (v.x - mean) * rr, qn1 = (v.y - mean) * rr;
    float qn2 = (v.z - mean) * rr, qn3 = (v.w - mean) * rr;
    float4 cs4 = *(const float4*)&rope[(size_t)(w * NQc + qrow) * 64 + c4 * 4];
    union { __hip_bfloat16 hh[4]; uint2 u; } pk;
    pk.hh[0] = __float2bfloat16(qn0 * cs4.x - qn1 * cs4.y);
    pk.hh[1] = __float2bfloat16(qn0 * cs4.y + qn1 * cs4.x);
    pk.hh[2] = __float2bfloat16(qn2 * cs4.z - qn3 * cs4.w);
    pk.hh[3] = __float2bfloat16(qn2 * cs4.w + qn3 * cs4.z);
    *(uint2*)(void*)&qs[qrow * LQ + c4 * 4] = pk.u;
  }
  // stage k (fused LN + table RoPE, row-major) and v (raw, transposed)
  for (int e = t; e < 2048; e += 256) {
    int kk = e >> 4, c4 = e & 15;
    int jc = min(max(j0 + kk, 0), Nc - 1);
    size_t src = (size_t)(b * Nc + jc) * QS + h * DHc + c4 * 4;
    float4 kv = *(const float4*)&qkvg[src + DIMc];
    float4 vv = *(const float4*)&qkvg[src + 2 * DIMc];
    float s = kv.x + kv.y + kv.z + kv.w;
    float s2 = kv.x * kv.x + kv.y * kv.y + kv.z * kv.z + kv.w * kv.w;
#pragma unroll
    for (int off = 1; off < 16; off <<= 1) {
      s += __shfl_xor(s, off, 64);
      s2 += __shfl_xor(s2, off, 64);
    }
    float mean = s * (1.0f / 64.0f);
    float rr = rsqrtf(s2 * (1.0f / 64.0f) - mean * mean + 1e-5f);
    float kn0 = (kv.x - mean) * rr, kn1 = (kv.y - mean) * rr;
    float kn2 = (kv.z - mean) * rr, kn3 = (kv.w - mean) * rr;
    float4 cs4 = *(const float4*)&rope[(size_t)jc * 64 + c4 * 4];
    union { __hip_bfloat16 hh[4]; uint2 u; } pk;
    pk.hh[0] = __float2bfloat16(kn0 * cs4.x - kn1 * cs4.y);
    pk.hh[1] = __float2bfloat16(kn0 * cs4.y + kn1 * cs4.x);
    pk.hh[2] = __float2bfloat16(kn2 * cs4.z - kn3 * cs4.w);
    pk.hh[3] = __float2bfloat16(kn2 * cs4.w + kn3 * cs4.z);
    *(uint2*)(void*)&ks[kk * LQ + c4 * 4] = pk.u;
    vT[(c4 * 4 + 0) * LV + kk] = __float2bfloat16(vv.x);
    vT[(c4 * 4 + 1) * LV + kk] = __float2bfloat16(vv.y);
    vT[(c4 * 4 + 2) * LV + kk] = __float2bfloat16(vv.z);
    vT[(c4 * 4 + 3) * LV + kk] = __float2bfloat16(vv.w);
  }
  // pre-fill score buffer with bias or -inf (mask/validity)
  for (int e = t; e < 4096; e += 256) {
    int qrow = e >> 7, key = e & 127;
    int j = j0 + key;
    bool valid = (j >= 0) && (j < Nc);
    int jc = min(max(j, 0), Nc - 1);
    float pm = pair_mask[((size_t)(b * Nc + w * NQc + qrow)) * Nc + jc];
    bool ok = valid && (pm > 0.f);
    sc[qrow * LS + key] = ok ? biasw[((size_t)blk * 32 + qrow) * 128 + key] : -1e30f;
  }
  __syncthreads();
  int lane = t & 63, wv = t >> 6;
  int l16 = lane & 15, quad = lane >> 4;
  // QK^T: wave wv handles keys [wv*32, wv*32+32), both m-tiles
  {
    short8 bfr[2][2];
#pragma unroll
    for (int nt = 0; nt < 2; ++nt)
#pragma unroll
      for (int k2 = 0; k2 < 2; ++k2)
        bfr[nt][k2] = *(const short8*)(const void*)&ks[(wv * 32 + nt * 16 + l16) * LQ + k2 * 32 + quad * 8];
#pragma unroll
    for (int mi = 0; mi < 2; ++mi) {
      short8 afr[2];
#pragma unroll
      for (int k2 = 0; k2 < 2; ++k2)
        afr[k2] = *(const short8*)(const void*)&qs[(mi * 16 + l16) * LQ + k2 * 32 + quad * 8];
#pragma unroll
      for (int nt = 0; nt < 2; ++nt) {
        floatx4 acc = (floatx4){0.f, 0.f, 0.f, 0.f};
        acc = __builtin_amdgcn_mfma_f32_16x16x32_bf16(afr[0], bfr[nt][0], acc, 0, 0, 0);
        acc = __builtin_amdgcn_mfma_f32_16x16x32_bf16(afr[1], bfr[nt][1], acc, 0, 0, 0);
        int key = wv * 32 + nt * 16 + l16;
#pragma unroll
        for (int r = 0; r < 4; ++r) {
          int m = mi * 16 + quad * 4 + r;
          float sv = sc[m * LS + key];
          if (sv > -1e29f) sc[m * LS + key] = sv + acc[r] * 0.125f;
        }
      }
    }
  }
  __syncthreads();
  // softmax: wave per 8 rows, write P as bf16
#pragma unroll
  for (int rr = 0; rr < 8; ++rr) {
    int qq = wv * 8 + rr;
    float v0 = sc[qq * LS + lane], v1 = sc[qq * LS + 64 + lane];
    float mx = wave_max(fmaxf(v0, v1));
    float e0 = expf(v0 - mx), e1 = expf(v1 - mx);
    float inv = 1.0f / wave_sum(e0 + e1);
    scP[qq * LP + lane] = __float2bfloat16(e0 * inv);
    scP[qq * LP + 64 + lane] = __float2bfloat16(e1 * inv);
  }
  __syncthreads();
  // PV: wave wv handles d-range [wv*16, wv*16+16), both m-tiles
  {
    short8 vb[4];
#pragma unroll
    for (int k4 = 0; k4 < 4; ++k4)
      vb[k4] = *(const short8*)(const void*)&vT[(wv * 16 + l16) * LV + k4 * 32 + quad * 8];
#pragma unroll
    for (int mi = 0; mi < 2; ++mi) {
      floatx4 acc = (floatx4){0.f, 0.f, 0.f, 0.f};
#pragma unroll
      for (int k4 = 0; k4 < 4; ++k4) {
        short8 pa = *(const short8*)(const void*)&scP[(mi * 16 + l16) * LP + k4 * 32 + quad * 8];
        acc = __builtin_amdgcn_mfma_f32_16x16x32_bf16(pa, vb[k4], acc, 0, 0, 0);
      }
      int d = wv * 16 + l16;
#pragma unroll
      for (int r = 0; r < 4; ++r) {
        int m = mi * 16 + quad * 4 + r;
        size_t mrow = (size_t)(b * Nc + w * NQc + m);
        float g = qkvg[mrow * QS + 3 * DIMc + h * DHc + d];
        o[mrow * DIMc + h * DHc + d] = __float2bfloat16(acc[r] * sigmoidf(g));
      }
    }
  }
}

extern "C" void kernel_launch(void* const* d_in, const int* in_sizes, int n_in,
                              void* d_out, int out_size, void* d_ws, size_t ws_size,
                              hipStream_t stream) {
  const float* x        = (const float*)d_in[0];
  const float* pair_rep = (const float*)d_in[1];
  const float* cond     = (const float*)d_in[2];
  const float* mask     = (const float*)d_in[3];
  const float* pair_mask= (const float*)d_in[4];
  const float* a1_gw    = (const float*)d_in[5];
  const float* a1_gb    = (const float*)d_in[6];
  const float* a1_bw    = (const float*)d_in[7];
  const float* wq       = (const float*)d_in[8];
  const float* bq       = (const float*)d_in[9];
  const float* wk       = (const float*)d_in[10];
  const float* bk       = (const float*)d_in[11];
  const float* wv       = (const float*)d_in[12];
  const float* bv       = (const float*)d_in[13];
  const float* wg       = (const float*)d_in[14];
  const float* bg       = (const float*)d_in[15];
  const float* wb_pair  = (const float*)d_in[16];
  const float* wo       = (const float*)d_in[17];
  const float* bo       = (const float*)d_in[18];
  const float* s1_w     = (const float*)d_in[19];
  const float* s1_b     = (const float*)d_in[20];
  const float* a2_gw    = (const float*)d_in[21];
  const float* a2_gb    = (const float*)d_in[22];
  const float* a2_bw    = (const float*)d_in[23];
  const float* tr_win   = (const float*)d_in[24];
  const float* tr_wout  = (const float*)d_in[25];
  const float* s2_w     = (const float*)d_in[26];
  const float* s2_b     = (const float*)d_in[27];
  float* out = (float*)d_out;

  const int M = Bc * Nc;  // 1024
  char* wsb = (char*)d_ws;
  size_t off = 0;
  auto alloc = [&](size_t bytes) { void* p = wsb + off; off += (bytes + 255) & ~(size_t)255; return p; };

  __hip_bfloat16* cnb     = (__hip_bfloat16*)alloc((size_t)M * DCONDc * 2);
  __hip_bfloat16* Wc6t    = (__hip_bfloat16*)alloc((size_t)6 * DIMc * DCONDc * 2);
  __hip_bfloat16* Wqkvg5t = (__hip_bfloat16*)alloc((size_t)5 * DIMc * DIMc * 2);
  __hip_bfloat16* twint   = (__hip_bfloat16*)alloc((size_t)2 * INNERc * DIMc * 2);
  __hip_bfloat16* twoutt  = (__hip_bfloat16*)alloc((size_t)DIMc * INNERc * 2);
  float* cb6    = (float*)alloc((size_t)6 * DIMc * 4);
  float* bqkvg  = (float*)alloc((size_t)4 * DIMc * 4);
  __hip_bfloat16* wbT = (__hip_bfloat16*)alloc((size_t)16 * DPAIRc * 2);
  float* colsum = (float*)alloc(16 * 4);
  float* rope   = (float*)alloc((size_t)Nc * 64 * 4);   // [pos][i](cos,sin)
  float* proj_c = (float*)alloc((size_t)M * 6 * DIMc * 4);
  float* xm     = (float*)alloc((size_t)M * DIMc * 4);
  __hip_bfloat16* xa = (__hip_bfloat16*)alloc((size_t)M * DIMc * 2);
  float* qkvg   = (float*)alloc((size_t)M * 4 * DIMc * 4);
  float* biasw  = (float*)alloc((size_t)Bc * Hc * NWc * NQc * NKc * 4);
  __hip_bfloat16* obg = (__hip_bfloat16*)alloc((size_t)M * DIMc * 2);
  float* x2     = (float*)alloc((size_t)M * DIMc * 4);
  __hip_bfloat16* xt = (__hip_bfloat16*)alloc((size_t)M * DIMc * 2);
  __hip_bfloat16* actb = (__hip_bfloat16*)alloc((size_t)M * INNERc * 2);
  __hip_bfloat16* wot = Wqkvg5t + (size_t)4 * DIMc * DIMc;
  (void)ws_size; (void)in_sizes; (void)n_in; (void)out_size;

  dim3 blk(256);

  PrepArgs pa;
  pa.a1_gw = a1_gw; pa.a1_bw = a1_bw; pa.s1_w = s1_w;
  pa.a2_gw = a2_gw; pa.a2_bw = a2_bw; pa.s2_w = s2_w;
  pa.wq = wq; pa.wk = wk; pa.wv = wv; pa.wg = wg; pa.wo = wo;
  pa.tr_win = tr_win; pa.tr_wout = tr_wout;
  pa.cond = cond;
  pa.a1_gb = a1_gb; pa.s1_b = s1_b; pa.a2_gb = a2_gb; pa.s2_b = s2_b;
  pa.bq = bq; pa.bk = bk; pa.bv = bv; pa.bg = bg; pa.wb_pair = wb_pair;
  pa.Wc6t = Wc6t; pa.Wqkvg5t = Wqkvg5t; pa.twint = twint; pa.twoutt = twoutt;
  pa.cnb = cnb; pa.wbT = wbT;
  pa.cb6 = cb6; pa.bqkvg = bqkvg; pa.colsum = colsum; pa.rope = rope;
  prep_k<<<PR_RT, blk, 0, stream>>>(pa);

  gemm_bf16_k<4><<<dim3(6 * DIMc / 128, M / 64), blk, 0, stream>>>(
      cnb, Wc6t, proj_c, M, 6 * DIMc, DCONDc, cb6, nullptr, 0, nullptr, nullptr, 0);

  adaln_apply_k<<<M, blk, 0, stream>>>(x, mask, proj_c + 0, proj_c + DIMc, 6 * DIMc, xa, xm);

  gemm_bf16_k<4><<<dim3(4 * DIMc / 128, M / 64), blk, 0, stream>>>(
      xa, Wqkvg5t, qkvg, M, 4 * DIMc, DIMc, bqkvg, nullptr, 0, nullptr, nullptr, 0);

  pair_bias_mfma_k<<<Bc * Nc, blk, 0, stream>>>(pair_rep, wbT, colsum, biasw);

  wattn_k<<<Bc * Hc * NWc, blk, 0, stream>>>(qkvg, biasw, pair_mask, rope, obg);

  gemm_bf16_k<1><<<dim3(DIMc / 32, M / 64), blk, 0, stream>>>(
      obg, wot, x2, M, DIMc, DIMc, bo, proj_c + 2 * DIMc, 6 * DIMc, xm, mask, 1);

  adaln_apply_k<<<M, blk, 0, stream>>>(x2, mask, proj_c + 3 * DIMc, proj_c + 4 * DIMc,
                                       6 * DIMc, xt, nullptr);

  gemm_bf16_k<4><<<dim3(2 * INNERc / 128, M / 64), blk, 0, stream>>>(
      xt, twint, (float*)actb, M, 2 * INNERc, DIMc, nullptr, nullptr, 0, nullptr, nullptr, 3);

  gemm_bf16_k<1><<<dim3(DIMc / 32, M / 64), blk, 0, stream>>>(
      actb, twoutt, out, M, DIMc, INNERc, nullptr, proj_c + 5 * DIMc, 6 * DIMc, x2, mask, 2);
}